// Round 1
// baseline (4525.851 us; speedup 1.0000x reference)
//
#include <hip/hip_runtime.h>
#include <math.h>

#define BATCH 16
#define SRCLEN 128
#define DIM 512
#define VOCABSZ 32000
#define BEAM 4
#define MAXLEN 16
#define NROWS (BATCH*BEAM)   // 64
#define BOS_TOK 1
#define EOS_TOK 2
#define NEGINF 1e9f

// ---------------- encoder pool: pooled[b][d] = masked mean of E_src[src[b,s]] ----------------
__global__ __launch_bounds__(512) void k_pool(const int* __restrict__ src,
                                              const float* __restrict__ Esrc,
                                              float* __restrict__ pooled) {
    int b = blockIdx.x;
    int d = threadIdx.x;
    float acc = 0.f, cnt = 0.f;
    for (int s = 0; s < SRCLEN; ++s) {
        int tok = src[b * SRCLEN + s];
        if (tok != 0) { acc += Esrc[(size_t)tok * DIM + d]; cnt += 1.f; }
    }
    pooled[b * DIM + d] = acc / fmaxf(cnt, 1.f);
}

// ---------------- state init ----------------
__global__ __launch_bounds__(1024) void k_init(int* __restrict__ alive_seq, float* __restrict__ alive_lp,
                                               int* __restrict__ fin_seq, float* __restrict__ fin_scores,
                                               int* __restrict__ fin_flags, int* __restrict__ batch_fin) {
    int tid = threadIdx.x;  // 1024 = NROWS*MAXLEN
    alive_seq[tid] = (tid % MAXLEN == 0) ? BOS_TOK : 0;
    fin_seq[tid] = 0;
    if (tid < NROWS) {
        alive_lp[tid] = (tid % BEAM == 0) ? 0.f : -INFINITY;
        fin_scores[tid] = -NEGINF;
        fin_flags[tid] = 0;
    }
    if (tid < BATCH) batch_fin[tid] = 0;
}

// ---------------- decoder input, transposed: xT[d][i] = E_tgt[last_i][d] + pooled[i/BEAM][d] ----------------
__global__ __launch_bounds__(512) void k_x(const float* __restrict__ Etgt,
                                           const float* __restrict__ pooled,
                                           const int* __restrict__ alive_seq, int t,
                                           float* __restrict__ xT) {
    int i = blockIdx.x;   // row 0..63
    int d = threadIdx.x;  // 0..511
    int last = alive_seq[i * MAXLEN + t];
    float v = Etgt[(size_t)last * DIM + d] + pooled[(i >> 2) * DIM + d];
    xT[d * NROWS + i] = v;
}

// ---------------- logits GEMM: logits[i][v] = sum_d xT[d][i]*W[d][v] + b[v] ----------------
// xT reads are wave-uniform -> scalar loads; W reads coalesced over v.
__global__ __launch_bounds__(256) void k_gemm(const float* __restrict__ xT,
                                              const float* __restrict__ W,
                                              const float* __restrict__ bias,
                                              float* __restrict__ logits) {
    int v = blockIdx.x * 256 + threadIdx.x;
    int r0 = blockIdx.y * 32;
    float acc[32];
#pragma unroll
    for (int i = 0; i < 32; ++i) acc[i] = 0.f;
    for (int d = 0; d < DIM; ++d) {
        float w = W[(size_t)d * VOCABSZ + v];
        const float* xr = xT + d * NROWS + r0;  // uniform address -> s_load
#pragma unroll
        for (int i = 0; i < 32; ++i) acc[i] = fmaf(xr[i], w, acc[i]);
    }
    float bb = bias[v];
#pragma unroll
    for (int i = 0; i < 32; ++i) logits[(size_t)(r0 + i) * VOCABSZ + v] = acc[i] + bb;
}

// ---------------- per-row: max, log(sum(exp)), top-8 (value desc, index asc) ----------------
__global__ __launch_bounds__(256) void k_rowred(const float* __restrict__ logits,
                                                float* __restrict__ rowm, float* __restrict__ rowlse,
                                                float* __restrict__ topv, int* __restrict__ topi) {
    int row = blockIdx.x;
    int tid = threadIdx.x;
    const float* lr = logits + (size_t)row * VOCABSZ;

    float lv[8]; int li[8];
#pragma unroll
    for (int j = 0; j < 8; ++j) { lv[j] = -INFINITY; li[j] = 0x7FFFFFFF; }
    for (int v = tid; v < VOCABSZ; v += 256) {
        float x = lr[v];
        if (x > lv[7] || (x == lv[7] && v < li[7])) {
            lv[7] = x; li[7] = v;
#pragma unroll
            for (int j = 7; j > 0; --j) {
                bool sw = (lv[j] > lv[j-1]) || (lv[j] == lv[j-1] && li[j] < li[j-1]);
                if (sw) { float tv = lv[j]; lv[j] = lv[j-1]; lv[j-1] = tv;
                          int  ti = li[j]; li[j] = li[j-1]; li[j-1] = ti; }
            }
        }
    }

    __shared__ float sred[256];
    sred[tid] = lv[0];
    __syncthreads();
    for (int s = 128; s > 0; s >>= 1) { if (tid < s) sred[tid] = fmaxf(sred[tid], sred[tid+s]); __syncthreads(); }
    float m = sred[0];
    __syncthreads();

    float se = 0.f;
    for (int v = tid; v < VOCABSZ; v += 256) se += expf(lr[v] - m);
    sred[tid] = se;
    __syncthreads();
    for (int s = 128; s > 0; s >>= 1) { if (tid < s) sred[tid] += sred[tid+s]; __syncthreads(); }
    if (tid == 0) { rowm[row] = m; rowlse[row] = logf(sred[0]); }

    // merge per-thread top-8 lists -> global top-8, key = (ordered float, ~index)
    __shared__ unsigned long long skey[256];
    int pos = 0;
    for (int r = 0; r < 8; ++r) {
        unsigned long long mykey = 0ULL;
        if (pos < 8) {
            unsigned int fb = __float_as_uint(lv[pos]);
            fb = fb ^ ((fb >> 31) ? 0xFFFFFFFFu : 0x80000000u);
            mykey = ((unsigned long long)fb << 32) | (unsigned long long)(0xFFFFFFFFu - (unsigned int)li[pos]);
        }
        skey[tid] = mykey;
        __syncthreads();
        for (int s = 128; s > 0; s >>= 1) { if (tid < s) skey[tid] = (skey[tid] > skey[tid+s]) ? skey[tid] : skey[tid+s]; __syncthreads(); }
        unsigned long long best = skey[0];
        __syncthreads();
        if (mykey == best && mykey != 0ULL) {
            topv[row * 8 + r] = lv[pos];
            topi[row * 8 + r] = li[pos];
            pos++;
        }
        __syncthreads();
    }
}

// ---------------- merge candidates + beam bookkeeping, one block per batch ----------------
__global__ __launch_bounds__(64) void k_select(const float* __restrict__ topv, const int* __restrict__ topi,
                                               const float* __restrict__ rowm, const float* __restrict__ rowlse,
                                               int* __restrict__ alive_seq, float* __restrict__ alive_lp,
                                               int* __restrict__ fin_seq, float* __restrict__ fin_scores,
                                               int* __restrict__ fin_flags, int* __restrict__ batch_fin, int t) {
    int b = blockIdx.x;
    int tid = threadIdx.x;
    __shared__ float cval[32]; __shared__ int cid[32];
    __shared__ int aseq_old[BEAM][MAXLEN]; __shared__ int fseq_old[BEAM][MAXLEN];
    __shared__ float alp_old[BEAM]; __shared__ float fsc_old[BEAM]; __shared__ int ffl_old[BEAM];
    __shared__ float tscore[8], tlp[8]; __shared__ int ttok[8], tbeam[8], tfin[8];
    __shared__ int aidx[4], fidx[4];
    __shared__ float nfsc[4]; __shared__ int nffl[4];
    float lpen = (float)(t + 1);

    if (tid < BEAM) {
        alp_old[tid] = alive_lp[b * BEAM + tid];
        fsc_old[tid] = fin_scores[b * BEAM + tid];
        ffl_old[tid] = fin_flags[b * BEAM + tid];
    }
    { int k = tid >> 4, p = tid & 15;
      aseq_old[k][p] = alive_seq[(b * BEAM + k) * MAXLEN + p];
      fseq_old[k][p] = fin_seq[(b * BEAM + k) * MAXLEN + p]; }
    __syncthreads();

    if (tid < 32) {
        int k = tid >> 3, j = tid & 7;
        int row = b * BEAM + k;
        float rv = topv[row * 8 + j];
        int vi = topi[row * 8 + j];
        float sh = rv - rowm[row];
        float lp = sh - rowlse[row];
        float full = alp_old[k] + lp;
        cval[tid] = full / lpen;                 // == reference flat score
        cid[tid]  = k * VOCABSZ + vi;            // flat index for tie-break
    }
    __syncthreads();
    int bf_old = batch_fin[b];

    if (tid == 0) {
        // top-8 of 32 candidates, (value desc, flat id asc) == lax.top_k stable order
        unsigned int used = 0;
        for (int r = 0; r < 8; ++r) {
            int best = -1;
            for (int j = 0; j < 32; ++j) {
                if (used & (1u << j)) continue;
                if (best < 0 || cval[j] > cval[best] ||
                    (cval[j] == cval[best] && cid[j] < cid[best])) best = j;
            }
            used |= 1u << best;
            float sc = cval[best]; int id = cid[best];
            tscore[r] = sc;
            tlp[r] = sc * lpen;                  // topk_lp = topk_scores * lpen (match ref rounding)
            ttok[r] = id % VOCABSZ;
            tbeam[r] = id / VOCABSZ;
            tfin[r] = (ttok[r] == EOS_TOK) ? 1 : 0;
        }
        // alive selection: top-4 of curr, ties by position asc
        float curr[8];
        for (int j = 0; j < 8; ++j) curr[j] = tscore[j] + (tfin[j] ? -NEGINF : 0.0f);
        unsigned int u2 = 0;
        for (int r = 0; r < 4; ++r) {
            int best = -1;
            for (int j = 0; j < 8; ++j) {
                if (u2 & (1u << j)) continue;
                if (best < 0 || curr[j] > curr[best]) best = j;
            }
            u2 |= 1u << best; aidx[r] = best;
        }
        // finished selection: cand = [old fin (4), fs (8)], top-4 ties by position asc
        float fscand[12]; int fflcand[12];
        for (int j = 0; j < 4; ++j) { fscand[j] = fsc_old[j]; fflcand[j] = ffl_old[j]; }
        for (int q = 0; q < 8; ++q) {
            float t1 = tscore[q] + (tfin[q] ? 0.0f : -NEGINF);
            float t2 = t1 + (bf_old ? -NEGINF : 0.0f);
            fscand[4 + q] = t2; fflcand[4 + q] = tfin[q];
        }
        unsigned int u3 = 0;
        for (int r = 0; r < 4; ++r) {
            int best = -1;
            for (int j = 0; j < 12; ++j) {
                if (u3 & (1u << j)) continue;
                if (best < 0 || fscand[j] > fscand[best]) best = j;
            }
            u3 |= 1u << best; fidx[r] = best;
            nfsc[r] = fscand[best]; nffl[r] = fflcand[best];
        }
    }
    __syncthreads();

    // write new sequences (gather from OLD alive_seq through tbeam, set token at t+1)
    { int k = tid >> 4, p = tid & 15;
      int j = aidx[k];
      int val = (p == t + 1) ? ttok[j] : aseq_old[tbeam[j]][p];
      alive_seq[(b * BEAM + k) * MAXLEN + p] = val;
      int fi = fidx[k]; int fval;
      if (fi < 4) fval = fseq_old[fi][p];
      else { int q = fi - 4; fval = (p == t + 1) ? ttok[q] : aseq_old[tbeam[q]][p]; }
      fin_seq[(b * BEAM + k) * MAXLEN + p] = fval; }

    if (tid < 4) {
        alive_lp[b * BEAM + tid] = tlp[aidx[tid]];
        fin_scores[b * BEAM + tid] = nfsc[tid];
        fin_flags[b * BEAM + tid] = nffl[tid];
    }
    if (tid == 0) {
        float lb = tlp[aidx[0]] / lpen;
        float lowest = nfsc[0] * (nffl[0] ? 1.f : 0.f);
        int allf = nffl[0];
        for (int k2 = 1; k2 < 4; ++k2) {
            float pz = nfsc[k2] * (nffl[k2] ? 1.f : 0.f);
            lowest = fminf(lowest, pz);
            allf = allf && nffl[k2];
        }
        lowest = lowest + (allf ? 0.f : -NEGINF);
        batch_fin[b] = bf_old || (lowest >= lb);
    }
}

// ---------------- output: fin_seq[:,0,:] as float ----------------
__global__ __launch_bounds__(256) void k_out(const int* __restrict__ fin_seq, float* __restrict__ out) {
    int tid = threadIdx.x;
    if (tid < BATCH * MAXLEN) {
        int b = tid / MAXLEN, p = tid % MAXLEN;
        out[tid] = (float)fin_seq[(b * BEAM + 0) * MAXLEN + p];
    }
}

extern "C" void kernel_launch(void* const* d_in, const int* in_sizes, int n_in,
                              void* d_out, int out_size, void* d_ws, size_t ws_size,
                              hipStream_t stream) {
    const int*   src  = (const int*)d_in[0];
    const float* Esrc = (const float*)d_in[1];
    const float* Etgt = (const float*)d_in[2];
    const float* W    = (const float*)d_in[3];
    const float* bias = (const float*)d_in[4];
    float* out = (float*)d_out;

    char* p = (char*)d_ws;
    float* logits     = (float*)p; p += (size_t)NROWS * VOCABSZ * 4;
    float* pooled     = (float*)p; p += BATCH * DIM * 4;
    float* xT         = (float*)p; p += DIM * NROWS * 4;
    float* rowm       = (float*)p; p += NROWS * 4;
    float* rowlse     = (float*)p; p += NROWS * 4;
    float* topv       = (float*)p; p += NROWS * 8 * 4;
    int*   topi       = (int*)p;   p += NROWS * 8 * 4;
    int*   alive_seq  = (int*)p;   p += NROWS * MAXLEN * 4;
    int*   fin_seq    = (int*)p;   p += NROWS * MAXLEN * 4;
    float* alive_lp   = (float*)p; p += NROWS * 4;
    float* fin_scores = (float*)p; p += NROWS * 4;
    int*   fin_flags  = (int*)p;   p += NROWS * 4;
    int*   batch_fin  = (int*)p;   p += BATCH * 4;

    k_pool<<<BATCH, DIM, 0, stream>>>(src, Esrc, pooled);
    k_init<<<1, 1024, 0, stream>>>(alive_seq, alive_lp, fin_seq, fin_scores, fin_flags, batch_fin);
    for (int t = 0; t < MAXLEN - 1; ++t) {
        k_x<<<NROWS, DIM, 0, stream>>>(Etgt, pooled, alive_seq, t, xT);
        k_gemm<<<dim3(VOCABSZ / 256, 2), 256, 0, stream>>>(xT, W, bias, logits);
        k_rowred<<<NROWS, 256, 0, stream>>>(logits, rowm, rowlse, topv, topi);
        k_select<<<BATCH, 64, 0, stream>>>(topv, topi, rowm, rowlse, alive_seq, alive_lp,
                                           fin_seq, fin_scores, fin_flags, batch_fin, t);
    }
    k_out<<<1, 256, 0, stream>>>(fin_seq, out);
}

// Round 2
// 3147.789 us; speedup vs baseline: 1.4378x; 1.4378x over previous
//
#include <hip/hip_runtime.h>
#include <math.h>

#define BATCH 16
#define SRCLEN 128
#define DIM 512
#define VOCABSZ 32000
#define BEAM 4
#define MAXLEN 16
#define NROWS (BATCH*BEAM)   // 64
#define BOS_TOK 1
#define EOS_TOK 2
#define NEGINF 1e9f
#define CHUNKS 8
#define CHUNK 4000           // VOCABSZ / CHUNKS

// ---------------- encoder pool: pooled[b][d] = masked mean of E_src[src[b,s]] ----------------
__global__ __launch_bounds__(512) void k_pool(const int* __restrict__ src,
                                              const float* __restrict__ Esrc,
                                              float* __restrict__ pooled) {
    int b = blockIdx.x;
    int d = threadIdx.x;
    float acc = 0.f, cnt = 0.f;
    for (int s = 0; s < SRCLEN; ++s) {
        int tok = src[b * SRCLEN + s];
        if (tok != 0) { acc += Esrc[(size_t)tok * DIM + d]; cnt += 1.f; }
    }
    pooled[b * DIM + d] = acc / fmaxf(cnt, 1.f);
}

// ---------------- state init ----------------
__global__ __launch_bounds__(1024) void k_init(int* __restrict__ alive_seq, float* __restrict__ alive_lp,
                                               int* __restrict__ fin_seq, float* __restrict__ fin_scores,
                                               int* __restrict__ fin_flags, int* __restrict__ batch_fin) {
    int tid = threadIdx.x;  // 1024 = NROWS*MAXLEN
    alive_seq[tid] = (tid % MAXLEN == 0) ? BOS_TOK : 0;
    fin_seq[tid] = 0;
    if (tid < NROWS) {
        alive_lp[tid] = (tid % BEAM == 0) ? 0.f : -INFINITY;
        fin_scores[tid] = -NEGINF;
        fin_flags[tid] = 0;
    }
    if (tid < BATCH) batch_fin[tid] = 0;
}

// ---------------- decoder input, grouped-transposed: xT[g][d][r] = E_tgt[last][d]+pooled ----------------
// layout [group 0..3][d 0..511][r 0..15] so the GEMM reads one s_load_dwordx16 per d.
__global__ __launch_bounds__(512) void k_x(const float* __restrict__ Etgt,
                                           const float* __restrict__ pooled,
                                           const int* __restrict__ alive_seq, int t,
                                           float* __restrict__ xT) {
    int i = blockIdx.x;   // row 0..63
    int d = threadIdx.x;  // 0..511
    int last = alive_seq[i * MAXLEN + t];
    float v = Etgt[(size_t)last * DIM + d] + pooled[(i >> 2) * DIM + d];
    int g = i >> 4, r = i & 15;
    xT[(g * DIM + d) * 16 + r] = v;
}

// ---------------- logits GEMM: logits[r0+i][v] = sum_d x[d][i]*W[d][v] + b[v] ----------------
// 500 blocks (125 v-tiles x 4 row-groups); x reads wave-uniform -> SGPR broadcast.
// FMA accumulation order per output element identical to round-0 (d ascending).
__global__ __launch_bounds__(256) void k_gemm(const float* __restrict__ xT,
                                              const float* __restrict__ W,
                                              const float* __restrict__ bias,
                                              float* __restrict__ logits) {
    int v = blockIdx.x * 256 + threadIdx.x;
    int g = blockIdx.y;
    const float* xg = xT + (size_t)g * DIM * 16;
    float acc[16];
#pragma unroll
    for (int i = 0; i < 16; ++i) acc[i] = 0.f;
    for (int d = 0; d < DIM; d += 4) {
        float w0 = W[(size_t)(d + 0) * VOCABSZ + v];
        float w1 = W[(size_t)(d + 1) * VOCABSZ + v];
        float w2 = W[(size_t)(d + 2) * VOCABSZ + v];
        float w3 = W[(size_t)(d + 3) * VOCABSZ + v];
        const float* x0 = xg + (d + 0) * 16;
        const float* x1 = xg + (d + 1) * 16;
        const float* x2 = xg + (d + 2) * 16;
        const float* x3 = xg + (d + 3) * 16;
#pragma unroll
        for (int i = 0; i < 16; ++i) acc[i] = fmaf(x0[i], w0, acc[i]);
#pragma unroll
        for (int i = 0; i < 16; ++i) acc[i] = fmaf(x1[i], w1, acc[i]);
#pragma unroll
        for (int i = 0; i < 16; ++i) acc[i] = fmaf(x2[i], w2, acc[i]);
#pragma unroll
        for (int i = 0; i < 16; ++i) acc[i] = fmaf(x3[i], w3, acc[i]);
    }
    float bb = bias[v];
    int r0 = g * 16;
#pragma unroll
    for (int i = 0; i < 16; ++i) logits[(size_t)(r0 + i) * VOCABSZ + v] = acc[i] + bb;
}

// ---------------- per-(row,chunk): partial max, sumexp, top-8 ----------------
// 512 blocks; each thread holds its 16 values in registers (single global pass).
__global__ __launch_bounds__(256) void k_part(const float* __restrict__ logits,
                                              float* __restrict__ pm, float* __restrict__ ps,
                                              float* __restrict__ ptopv, int* __restrict__ ptopi) {
    int row = blockIdx.x, ch = blockIdx.y;
    int tid = threadIdx.x;
    const float4* lr4 = (const float4*)(logits + (size_t)row * VOCABSZ + ch * CHUNK);

    float va[16]; int np = 0;
    float lv[8]; int li[8];
#pragma unroll
    for (int j = 0; j < 8; ++j) { lv[j] = -INFINITY; li[j] = 0x7FFFFFFF; }

#pragma unroll
    for (int j = 0; j < 4; ++j) {
        int idx = j * 256 + tid;
        if (idx < CHUNK / 4) {
            float4 q = lr4[idx];
            int gi = ch * CHUNK + idx * 4;
            float vals[4] = {q.x, q.y, q.z, q.w};
#pragma unroll
            for (int c = 0; c < 4; ++c) {
                float x = vals[c];
                va[np++] = x;
                int v = gi + c;
                if (x > lv[7] || (x == lv[7] && v < li[7])) {
                    lv[7] = x; li[7] = v;
#pragma unroll
                    for (int q2 = 7; q2 > 0; --q2) {
                        bool sw = (lv[q2] > lv[q2-1]) || (lv[q2] == lv[q2-1] && li[q2] < li[q2-1]);
                        if (sw) { float tv = lv[q2]; lv[q2] = lv[q2-1]; lv[q2-1] = tv;
                                  int  ti = li[q2]; li[q2] = li[q2-1]; li[q2-1] = ti; }
                    }
                }
            }
        }
    }

    // block max
    __shared__ float sred[256];
    float m_t = -INFINITY;
    for (int j = 0; j < np; ++j) m_t = fmaxf(m_t, va[j]);
    sred[tid] = m_t;
    __syncthreads();
    for (int s = 128; s > 0; s >>= 1) { if (tid < s) sred[tid] = fmaxf(sred[tid], sred[tid+s]); __syncthreads(); }
    float m = sred[0];
    __syncthreads();

    // block sumexp (values still in registers)
    float se = 0.f;
    for (int j = 0; j < np; ++j) se += expf(va[j] - m);
    sred[tid] = se;
    __syncthreads();
    for (int s = 128; s > 0; s >>= 1) { if (tid < s) sred[tid] += sred[tid+s]; __syncthreads(); }
    if (tid == 0) { pm[row * CHUNKS + ch] = m; ps[row * CHUNKS + ch] = sred[0]; }

    // merge per-thread top-8 -> block top-8 (value desc, index asc)
    __shared__ unsigned long long skey[256];
    int pos = 0;
    float* otv = ptopv + ((size_t)row * CHUNKS + ch) * 8;
    int*   oti = ptopi + ((size_t)row * CHUNKS + ch) * 8;
    for (int r = 0; r < 8; ++r) {
        unsigned long long mykey = 0ULL;
        if (pos < 8) {
            unsigned int fb = __float_as_uint(lv[pos]);
            fb = fb ^ ((fb >> 31) ? 0xFFFFFFFFu : 0x80000000u);
            mykey = ((unsigned long long)fb << 32) | (unsigned long long)(0xFFFFFFFFu - (unsigned int)li[pos]);
        }
        skey[tid] = mykey;
        __syncthreads();
        for (int s = 128; s > 0; s >>= 1) { if (tid < s) skey[tid] = (skey[tid] > skey[tid+s]) ? skey[tid] : skey[tid+s]; __syncthreads(); }
        unsigned long long best = skey[0];
        __syncthreads();
        if (mykey == best && mykey != 0ULL) {
            otv[r] = lv[pos];
            oti[r] = li[pos];
            pos++;
        }
        __syncthreads();
    }
}

// ---------------- merge chunk partials + beam bookkeeping, one block per batch ----------------
__global__ __launch_bounds__(64) void k_mergesel(const float* __restrict__ pm, const float* __restrict__ ps,
                                                 const float* __restrict__ ptopv, const int* __restrict__ ptopi,
                                                 int* __restrict__ alive_seq, float* __restrict__ alive_lp,
                                                 int* __restrict__ fin_seq, float* __restrict__ fin_scores,
                                                 int* __restrict__ fin_flags, int* __restrict__ batch_fin, int t) {
    int b = blockIdx.x;
    int tid = threadIdx.x;
    __shared__ float srm[4], srl[4], mtv[4][8]; __shared__ int mti[4][8];
    __shared__ float cval[32]; __shared__ int cid[32];
    __shared__ int aseq_old[BEAM][MAXLEN]; __shared__ int fseq_old[BEAM][MAXLEN];
    __shared__ float alp_old[BEAM]; __shared__ float fsc_old[BEAM]; __shared__ int ffl_old[BEAM];
    __shared__ float tscore[8], tlp[8]; __shared__ int ttok[8], tbeam[8], tfin[8];
    __shared__ int aidx[4], fidx[4];
    __shared__ float nfsc[4]; __shared__ int nffl[4];
    float lpen = (float)(t + 1);

    // per-row merge of chunk partials (threads 0..3, one row each)
    if (tid < 4) {
        int row = b * BEAM + tid;
        float m = -INFINITY;
        for (int c = 0; c < CHUNKS; ++c) m = fmaxf(m, pm[row * CHUNKS + c]);
        float s = 0.f;
        for (int c = 0; c < CHUNKS; ++c) s += ps[row * CHUNKS + c] * expf(pm[row * CHUNKS + c] - m);
        srm[tid] = m; srl[tid] = logf(s);
        const float* tv = ptopv + (size_t)row * CHUNKS * 8;
        const int*   ti = ptopi + (size_t)row * CHUNKS * 8;
        unsigned long long used = 0ULL;
        for (int r = 0; r < 8; ++r) {
            int best = -1;
            for (int j = 0; j < 64; ++j) {
                if ((used >> j) & 1ULL) continue;
                if (best < 0 || tv[j] > tv[best] || (tv[j] == tv[best] && ti[j] < ti[best])) best = j;
            }
            used |= 1ULL << best;
            mtv[tid][r] = tv[best]; mti[tid][r] = ti[best];
        }
    }

    if (tid < BEAM) {
        alp_old[tid] = alive_lp[b * BEAM + tid];
        fsc_old[tid] = fin_scores[b * BEAM + tid];
        ffl_old[tid] = fin_flags[b * BEAM + tid];
    }
    { int k = tid >> 4, p = tid & 15;
      aseq_old[k][p] = alive_seq[(b * BEAM + k) * MAXLEN + p];
      fseq_old[k][p] = fin_seq[(b * BEAM + k) * MAXLEN + p]; }
    __syncthreads();

    if (tid < 32) {
        int k = tid >> 3, j = tid & 7;
        float rv = mtv[k][j];
        int vi = mti[k][j];
        float sh = rv - srm[k];
        float lp = sh - srl[k];
        float full = alp_old[k] + lp;
        cval[tid] = full / lpen;                 // == reference flat score
        cid[tid]  = k * VOCABSZ + vi;            // flat index for tie-break
    }
    __syncthreads();
    int bf_old = batch_fin[b];

    if (tid == 0) {
        // top-8 of 32 candidates, (value desc, flat id asc) == lax.top_k stable order
        unsigned int used = 0;
        for (int r = 0; r < 8; ++r) {
            int best = -1;
            for (int j = 0; j < 32; ++j) {
                if (used & (1u << j)) continue;
                if (best < 0 || cval[j] > cval[best] ||
                    (cval[j] == cval[best] && cid[j] < cid[best])) best = j;
            }
            used |= 1u << best;
            float sc = cval[best]; int id = cid[best];
            tscore[r] = sc;
            tlp[r] = sc * lpen;                  // topk_lp = topk_scores * lpen (match ref rounding)
            ttok[r] = id % VOCABSZ;
            tbeam[r] = id / VOCABSZ;
            tfin[r] = (ttok[r] == EOS_TOK) ? 1 : 0;
        }
        // alive selection: top-4 of curr, ties by position asc
        float curr[8];
        for (int j = 0; j < 8; ++j) curr[j] = tscore[j] + (tfin[j] ? -NEGINF : 0.0f);
        unsigned int u2 = 0;
        for (int r = 0; r < 4; ++r) {
            int best = -1;
            for (int j = 0; j < 8; ++j) {
                if (u2 & (1u << j)) continue;
                if (best < 0 || curr[j] > curr[best]) best = j;
            }
            u2 |= 1u << best; aidx[r] = best;
        }
        // finished selection: cand = [old fin (4), fs (8)], top-4 ties by position asc
        float fscand[12]; int fflcand[12];
        for (int j = 0; j < 4; ++j) { fscand[j] = fsc_old[j]; fflcand[j] = ffl_old[j]; }
        for (int q = 0; q < 8; ++q) {
            float t1 = tscore[q] + (tfin[q] ? 0.0f : -NEGINF);
            float t2 = t1 + (bf_old ? -NEGINF : 0.0f);
            fscand[4 + q] = t2; fflcand[4 + q] = tfin[q];
        }
        unsigned int u3 = 0;
        for (int r = 0; r < 4; ++r) {
            int best = -1;
            for (int j = 0; j < 12; ++j) {
                if (u3 & (1u << j)) continue;
                if (best < 0 || fscand[j] > fscand[best]) best = j;
            }
            u3 |= 1u << best; fidx[r] = best;
            nfsc[r] = fscand[best]; nffl[r] = fflcand[best];
        }
    }
    __syncthreads();

    // write new sequences (gather from OLD alive_seq through tbeam, set token at t+1)
    { int k = tid >> 4, p = tid & 15;
      int j = aidx[k];
      int val = (p == t + 1) ? ttok[j] : aseq_old[tbeam[j]][p];
      alive_seq[(b * BEAM + k) * MAXLEN + p] = val;
      int fi = fidx[k]; int fval;
      if (fi < 4) fval = fseq_old[fi][p];
      else { int q = fi - 4; fval = (p == t + 1) ? ttok[q] : aseq_old[tbeam[q]][p]; }
      fin_seq[(b * BEAM + k) * MAXLEN + p] = fval; }

    if (tid < 4) {
        alive_lp[b * BEAM + tid] = tlp[aidx[tid]];
        fin_scores[b * BEAM + tid] = nfsc[tid];
        fin_flags[b * BEAM + tid] = nffl[tid];
    }
    if (tid == 0) {
        float lb = tlp[aidx[0]] / lpen;
        float lowest = nfsc[0] * (nffl[0] ? 1.f : 0.f);
        int allf = nffl[0];
        for (int k2 = 1; k2 < 4; ++k2) {
            float pz = nfsc[k2] * (nffl[k2] ? 1.f : 0.f);
            lowest = fminf(lowest, pz);
            allf = allf && nffl[k2];
        }
        lowest = lowest + (allf ? 0.f : -NEGINF);
        batch_fin[b] = bf_old || (lowest >= lb);
    }
}

// ---------------- output: fin_seq[:,0,:] as float ----------------
__global__ __launch_bounds__(256) void k_out(const int* __restrict__ fin_seq, float* __restrict__ out) {
    int tid = threadIdx.x;
    if (tid < BATCH * MAXLEN) {
        int b = tid / MAXLEN, p = tid % MAXLEN;
        out[tid] = (float)fin_seq[(b * BEAM + 0) * MAXLEN + p];
    }
}

extern "C" void kernel_launch(void* const* d_in, const int* in_sizes, int n_in,
                              void* d_out, int out_size, void* d_ws, size_t ws_size,
                              hipStream_t stream) {
    const int*   src  = (const int*)d_in[0];
    const float* Esrc = (const float*)d_in[1];
    const float* Etgt = (const float*)d_in[2];
    const float* W    = (const float*)d_in[3];
    const float* bias = (const float*)d_in[4];
    float* out = (float*)d_out;

    char* p = (char*)d_ws;
    float* logits     = (float*)p; p += (size_t)NROWS * VOCABSZ * 4;
    float* pooled     = (float*)p; p += BATCH * DIM * 4;
    float* xT         = (float*)p; p += DIM * NROWS * 4;
    float* pm         = (float*)p; p += NROWS * CHUNKS * 4;
    float* ps         = (float*)p; p += NROWS * CHUNKS * 4;
    float* ptopv      = (float*)p; p += NROWS * CHUNKS * 8 * 4;
    int*   ptopi      = (int*)p;   p += NROWS * CHUNKS * 8 * 4;
    int*   alive_seq  = (int*)p;   p += NROWS * MAXLEN * 4;
    int*   fin_seq    = (int*)p;   p += NROWS * MAXLEN * 4;
    float* alive_lp   = (float*)p; p += NROWS * 4;
    float* fin_scores = (float*)p; p += NROWS * 4;
    int*   fin_flags  = (int*)p;   p += NROWS * 4;
    int*   batch_fin  = (int*)p;   p += BATCH * 4;

    k_pool<<<BATCH, DIM, 0, stream>>>(src, Esrc, pooled);
    k_init<<<1, 1024, 0, stream>>>(alive_seq, alive_lp, fin_seq, fin_scores, fin_flags, batch_fin);
    for (int t = 0; t < MAXLEN - 1; ++t) {
        k_x<<<NROWS, DIM, 0, stream>>>(Etgt, pooled, alive_seq, t, xT);
        k_gemm<<<dim3(VOCABSZ / 256, 4), 256, 0, stream>>>(xT, W, bias, logits);
        k_part<<<dim3(NROWS, CHUNKS), 256, 0, stream>>>(logits, pm, ps, ptopv, ptopi);
        k_mergesel<<<BATCH, 64, 0, stream>>>(pm, ps, ptopv, ptopi, alive_seq, alive_lp,
                                             fin_seq, fin_scores, fin_flags, batch_fin, t);
    }
    k_out<<<1, 256, 0, stream>>>(fin_seq, out);
}

// Round 3
// 2918.005 us; speedup vs baseline: 1.5510x; 1.0787x over previous
//
#include <hip/hip_runtime.h>
#include <math.h>

#define BATCH 16
#define SRCLEN 128
#define DIM 512
#define VOCABSZ 32000
#define BEAM 4
#define MAXLEN 16
#define NROWS (BATCH*BEAM)   // 64
#define BOS_TOK 1
#define EOS_TOK 2
#define NEGINF 1e9f
#define CHUNKS 8
#define CHUNK 4000           // VOCABSZ / CHUNKS

// ---------------- encoder pool: pooled[b][d] = masked mean of E_src[src[b,s]] ----------------
__global__ __launch_bounds__(512) void k_pool(const int* __restrict__ src,
                                              const float* __restrict__ Esrc,
                                              float* __restrict__ pooled) {
    int b = blockIdx.x;
    int d = threadIdx.x;
    float acc = 0.f, cnt = 0.f;
    for (int s = 0; s < SRCLEN; ++s) {
        int tok = src[b * SRCLEN + s];
        if (tok != 0) { acc += Esrc[(size_t)tok * DIM + d]; cnt += 1.f; }
    }
    pooled[b * DIM + d] = acc / fmaxf(cnt, 1.f);
}

// ---------------- state init ----------------
__global__ __launch_bounds__(1024) void k_init(int* __restrict__ alive_seq, float* __restrict__ alive_lp,
                                               int* __restrict__ fin_seq, float* __restrict__ fin_scores,
                                               int* __restrict__ fin_flags, int* __restrict__ batch_fin) {
    int tid = threadIdx.x;  // 1024 = NROWS*MAXLEN
    alive_seq[tid] = (tid % MAXLEN == 0) ? BOS_TOK : 0;
    fin_seq[tid] = 0;
    if (tid < NROWS) {
        alive_lp[tid] = (tid % BEAM == 0) ? 0.f : -INFINITY;
        fin_scores[tid] = -NEGINF;
        fin_flags[tid] = 0;
    }
    if (tid < BATCH) batch_fin[tid] = 0;
}

// ---------------- decoder input, grouped-transposed: xT[g][d][r] = E_tgt[last][d]+pooled ----------------
__global__ __launch_bounds__(512) void k_x(const float* __restrict__ Etgt,
                                           const float* __restrict__ pooled,
                                           const int* __restrict__ alive_seq, int t,
                                           float* __restrict__ xT) {
    int i = blockIdx.x;   // row 0..63
    int d = threadIdx.x;  // 0..511
    int last = alive_seq[i * MAXLEN + t];
    float v = Etgt[(size_t)last * DIM + d] + pooled[(i >> 2) * DIM + d];
    int g = i >> 4, r = i & 15;
    xT[(g * DIM + d) * 16 + r] = v;
}

// ---------------- logits GEMM: logits[r0+i][v] = sum_d x[d][i]*W[d][v] + b[v] ----------------
__global__ __launch_bounds__(256) void k_gemm(const float* __restrict__ xT,
                                              const float* __restrict__ W,
                                              const float* __restrict__ bias,
                                              float* __restrict__ logits) {
    int v = blockIdx.x * 256 + threadIdx.x;
    int g = blockIdx.y;
    const float* xg = xT + (size_t)g * DIM * 16;
    float acc[16];
#pragma unroll
    for (int i = 0; i < 16; ++i) acc[i] = 0.f;
    for (int d = 0; d < DIM; d += 4) {
        float w0 = W[(size_t)(d + 0) * VOCABSZ + v];
        float w1 = W[(size_t)(d + 1) * VOCABSZ + v];
        float w2 = W[(size_t)(d + 2) * VOCABSZ + v];
        float w3 = W[(size_t)(d + 3) * VOCABSZ + v];
        const float* x0 = xg + (d + 0) * 16;
        const float* x1 = xg + (d + 1) * 16;
        const float* x2 = xg + (d + 2) * 16;
        const float* x3 = xg + (d + 3) * 16;
#pragma unroll
        for (int i = 0; i < 16; ++i) acc[i] = fmaf(x0[i], w0, acc[i]);
#pragma unroll
        for (int i = 0; i < 16; ++i) acc[i] = fmaf(x1[i], w1, acc[i]);
#pragma unroll
        for (int i = 0; i < 16; ++i) acc[i] = fmaf(x2[i], w2, acc[i]);
#pragma unroll
        for (int i = 0; i < 16; ++i) acc[i] = fmaf(x3[i], w3, acc[i]);
    }
    float bb = bias[v];
    int r0 = g * 16;
#pragma unroll
    for (int i = 0; i < 16; ++i) logits[(size_t)(r0 + i) * VOCABSZ + v] = acc[i] + bb;
}

// ---------------- per-(row,chunk): partial max, sumexp, top-8 ----------------
__global__ __launch_bounds__(256) void k_part(const float* __restrict__ logits,
                                              float* __restrict__ pm, float* __restrict__ ps,
                                              float* __restrict__ ptopv, int* __restrict__ ptopi) {
    int row = blockIdx.x, ch = blockIdx.y;
    int tid = threadIdx.x;
    const float4* lr4 = (const float4*)(logits + (size_t)row * VOCABSZ + ch * CHUNK);

    float va[16]; int np = 0;
    float lv[8]; int li[8];
#pragma unroll
    for (int j = 0; j < 8; ++j) { lv[j] = -INFINITY; li[j] = 0x7FFFFFFF; }

#pragma unroll
    for (int j = 0; j < 4; ++j) {
        int idx = j * 256 + tid;
        if (idx < CHUNK / 4) {
            float4 q = lr4[idx];
            int gi = ch * CHUNK + idx * 4;
            float vals[4] = {q.x, q.y, q.z, q.w};
#pragma unroll
            for (int c = 0; c < 4; ++c) {
                float x = vals[c];
                va[np++] = x;
                int v = gi + c;
                if (x > lv[7] || (x == lv[7] && v < li[7])) {
                    lv[7] = x; li[7] = v;
#pragma unroll
                    for (int q2 = 7; q2 > 0; --q2) {
                        bool sw = (lv[q2] > lv[q2-1]) || (lv[q2] == lv[q2-1] && li[q2] < li[q2-1]);
                        if (sw) { float tv = lv[q2]; lv[q2] = lv[q2-1]; lv[q2-1] = tv;
                                  int  ti = li[q2]; li[q2] = li[q2-1]; li[q2-1] = ti; }
                    }
                }
            }
        }
    }

    // block max
    __shared__ float sred[256];
    float m_t = -INFINITY;
    for (int j = 0; j < np; ++j) m_t = fmaxf(m_t, va[j]);
    sred[tid] = m_t;
    __syncthreads();
    for (int s = 128; s > 0; s >>= 1) { if (tid < s) sred[tid] = fmaxf(sred[tid], sred[tid+s]); __syncthreads(); }
    float m = sred[0];
    __syncthreads();

    // block sumexp (values still in registers)
    float se = 0.f;
    for (int j = 0; j < np; ++j) se += expf(va[j] - m);
    sred[tid] = se;
    __syncthreads();
    for (int s = 128; s > 0; s >>= 1) { if (tid < s) sred[tid] += sred[tid+s]; __syncthreads(); }
    if (tid == 0) { pm[row * CHUNKS + ch] = m; ps[row * CHUNKS + ch] = sred[0]; }

    // merge per-thread top-8 -> block top-8 (value desc, index asc)
    __shared__ unsigned long long skey[256];
    int pos = 0;
    float* otv = ptopv + ((size_t)row * CHUNKS + ch) * 8;
    int*   oti = ptopi + ((size_t)row * CHUNKS + ch) * 8;
    for (int r = 0; r < 8; ++r) {
        unsigned long long mykey = 0ULL;
        if (pos < 8) {
            unsigned int fb = __float_as_uint(lv[pos]);
            fb = fb ^ ((fb >> 31) ? 0xFFFFFFFFu : 0x80000000u);
            mykey = ((unsigned long long)fb << 32) | (unsigned long long)(0xFFFFFFFFu - (unsigned int)li[pos]);
        }
        skey[tid] = mykey;
        __syncthreads();
        for (int s = 128; s > 0; s >>= 1) { if (tid < s) skey[tid] = (skey[tid] > skey[tid+s]) ? skey[tid] : skey[tid+s]; __syncthreads(); }
        unsigned long long best = skey[0];
        __syncthreads();
        if (mykey == best && mykey != 0ULL) {
            otv[r] = lv[pos];
            oti[r] = li[pos];
            pos++;
        }
        __syncthreads();
    }
}

// ---------------- merge chunk partials + beam bookkeeping, one block per batch ----------------
// R2 fix: stage the 4x64 candidate lists + 4x8 (m,s) partials into LDS with all
// 64 threads BEFORE any serial scan. R1's version read global memory inside the
// O(8x64) selection loop -> 512 dependent ~500cyc loads -> 108us/dispatch.
__global__ __launch_bounds__(64) void k_mergesel(const float* __restrict__ pm, const float* __restrict__ ps,
                                                 const float* __restrict__ ptopv, const int* __restrict__ ptopi,
                                                 int* __restrict__ alive_seq, float* __restrict__ alive_lp,
                                                 int* __restrict__ fin_seq, float* __restrict__ fin_scores,
                                                 int* __restrict__ fin_flags, int* __restrict__ batch_fin, int t) {
    int b = blockIdx.x;
    int tid = threadIdx.x;
    __shared__ float stv[4][64]; __shared__ int sti[4][64];   // candidate lists in LDS
    __shared__ float spm[4][8], sps[4][8];                     // (m,s) partials in LDS
    __shared__ float srm[4], srl[4], mtv[4][8]; __shared__ int mti[4][8];
    __shared__ float cval[32]; __shared__ int cid[32];
    __shared__ int aseq_old[BEAM][MAXLEN]; __shared__ int fseq_old[BEAM][MAXLEN];
    __shared__ float alp_old[BEAM]; __shared__ float fsc_old[BEAM]; __shared__ int ffl_old[BEAM];
    __shared__ float tscore[8], tlp[8]; __shared__ int ttok[8], tbeam[8], tfin[8];
    __shared__ int aidx[4], fidx[4];
    __shared__ float nfsc[4]; __shared__ int nffl[4];
    float lpen = (float)(t + 1);

    // cooperative staging: 4 rows x 64 entries, each thread loads 4 (coalesced)
#pragma unroll
    for (int k = 0; k < 4; ++k) {
        int row = b * BEAM + k;
        stv[k][tid] = ptopv[(size_t)row * 64 + tid];
        sti[k][tid] = ptopi[(size_t)row * 64 + tid];
    }
    if (tid < 32) {
        int k = tid >> 3, c = tid & 7;
        spm[k][c] = pm[(b * BEAM + k) * CHUNKS + c];
        sps[k][c] = ps[(b * BEAM + k) * CHUNKS + c];
    }
    if (tid < BEAM) {
        alp_old[tid] = alive_lp[b * BEAM + tid];
        fsc_old[tid] = fin_scores[b * BEAM + tid];
        ffl_old[tid] = fin_flags[b * BEAM + tid];
    }
    { int k = tid >> 4, p = tid & 15;
      aseq_old[k][p] = alive_seq[(b * BEAM + k) * MAXLEN + p];
      fseq_old[k][p] = fin_seq[(b * BEAM + k) * MAXLEN + p]; }
    __syncthreads();

    // per-row merge of chunk partials (threads 0..3, one row each, all from LDS)
    if (tid < 4) {
        float m = -INFINITY;
        for (int c = 0; c < CHUNKS; ++c) m = fmaxf(m, spm[tid][c]);
        float s = 0.f;
        for (int c = 0; c < CHUNKS; ++c) s += sps[tid][c] * expf(spm[tid][c] - m);
        srm[tid] = m; srl[tid] = logf(s);
        unsigned long long used = 0ULL;
        for (int r = 0; r < 8; ++r) {
            int best = -1;
            for (int j = 0; j < 64; ++j) {
                if ((used >> j) & 1ULL) continue;
                if (best < 0 || stv[tid][j] > stv[tid][best] ||
                    (stv[tid][j] == stv[tid][best] && sti[tid][j] < sti[tid][best])) best = j;
            }
            used |= 1ULL << best;
            mtv[tid][r] = stv[tid][best]; mti[tid][r] = sti[tid][best];
        }
    }
    __syncthreads();

    if (tid < 32) {
        int k = tid >> 3, j = tid & 7;
        float rv = mtv[k][j];
        int vi = mti[k][j];
        float sh = rv - srm[k];
        float lp = sh - srl[k];
        float full = alp_old[k] + lp;
        cval[tid] = full / lpen;                 // == reference flat score
        cid[tid]  = k * VOCABSZ + vi;            // flat index for tie-break
    }
    __syncthreads();
    int bf_old = batch_fin[b];

    if (tid == 0) {
        // top-8 of 32 candidates, (value desc, flat id asc) == lax.top_k stable order
        unsigned int used = 0;
        for (int r = 0; r < 8; ++r) {
            int best = -1;
            for (int j = 0; j < 32; ++j) {
                if (used & (1u << j)) continue;
                if (best < 0 || cval[j] > cval[best] ||
                    (cval[j] == cval[best] && cid[j] < cid[best])) best = j;
            }
            used |= 1u << best;
            float sc = cval[best]; int id = cid[best];
            tscore[r] = sc;
            tlp[r] = sc * lpen;                  // topk_lp = topk_scores * lpen (match ref rounding)
            ttok[r] = id % VOCABSZ;
            tbeam[r] = id / VOCABSZ;
            tfin[r] = (ttok[r] == EOS_TOK) ? 1 : 0;
        }
        // alive selection: top-4 of curr, ties by position asc
        float curr[8];
        for (int j = 0; j < 8; ++j) curr[j] = tscore[j] + (tfin[j] ? -NEGINF : 0.0f);
        unsigned int u2 = 0;
        for (int r = 0; r < 4; ++r) {
            int best = -1;
            for (int j = 0; j < 8; ++j) {
                if (u2 & (1u << j)) continue;
                if (best < 0 || curr[j] > curr[best]) best = j;
            }
            u2 |= 1u << best; aidx[r] = best;
        }
        // finished selection: cand = [old fin (4), fs (8)], top-4 ties by position asc
        float fscand[12]; int fflcand[12];
        for (int j = 0; j < 4; ++j) { fscand[j] = fsc_old[j]; fflcand[j] = ffl_old[j]; }
        for (int q = 0; q < 8; ++q) {
            float t1 = tscore[q] + (tfin[q] ? 0.0f : -NEGINF);
            float t2 = t1 + (bf_old ? -NEGINF : 0.0f);
            fscand[4 + q] = t2; fflcand[4 + q] = tfin[q];
        }
        unsigned int u3 = 0;
        for (int r = 0; r < 4; ++r) {
            int best = -1;
            for (int j = 0; j < 12; ++j) {
                if (u3 & (1u << j)) continue;
                if (best < 0 || fscand[j] > fscand[best]) best = j;
            }
            u3 |= 1u << best; fidx[r] = best;
            nfsc[r] = fscand[best]; nffl[r] = fflcand[best];
        }
    }
    __syncthreads();

    // write new sequences (gather from OLD alive_seq through tbeam, set token at t+1)
    { int k = tid >> 4, p = tid & 15;
      int j = aidx[k];
      int val = (p == t + 1) ? ttok[j] : aseq_old[tbeam[j]][p];
      alive_seq[(b * BEAM + k) * MAXLEN + p] = val;
      int fi = fidx[k]; int fval;
      if (fi < 4) fval = fseq_old[fi][p];
      else { int q = fi - 4; fval = (p == t + 1) ? ttok[q] : aseq_old[tbeam[q]][p]; }
      fin_seq[(b * BEAM + k) * MAXLEN + p] = fval; }

    if (tid < 4) {
        alive_lp[b * BEAM + tid] = tlp[aidx[tid]];
        fin_scores[b * BEAM + tid] = nfsc[tid];
        fin_flags[b * BEAM + tid] = nffl[tid];
    }
    if (tid == 0) {
        float lb = tlp[aidx[0]] / lpen;
        float lowest = nfsc[0] * (nffl[0] ? 1.f : 0.f);
        int allf = nffl[0];
        for (int k2 = 1; k2 < 4; ++k2) {
            float pz = nfsc[k2] * (nffl[k2] ? 1.f : 0.f);
            lowest = fminf(lowest, pz);
            allf = allf && nffl[k2];
        }
        lowest = lowest + (allf ? 0.f : -NEGINF);
        batch_fin[b] = bf_old || (lowest >= lb);
    }
}

// ---------------- output: fin_seq[:,0,:] as float ----------------
__global__ __launch_bounds__(256) void k_out(const int* __restrict__ fin_seq, float* __restrict__ out) {
    int tid = threadIdx.x;
    if (tid < BATCH * MAXLEN) {
        int b = tid / MAXLEN, p = tid % MAXLEN;
        out[tid] = (float)fin_seq[(b * BEAM + 0) * MAXLEN + p];
    }
}

extern "C" void kernel_launch(void* const* d_in, const int* in_sizes, int n_in,
                              void* d_out, int out_size, void* d_ws, size_t ws_size,
                              hipStream_t stream) {
    const int*   src  = (const int*)d_in[0];
    const float* Esrc = (const float*)d_in[1];
    const float* Etgt = (const float*)d_in[2];
    const float* W    = (const float*)d_in[3];
    const float* bias = (const float*)d_in[4];
    float* out = (float*)d_out;

    char* p = (char*)d_ws;
    float* logits     = (float*)p; p += (size_t)NROWS * VOCABSZ * 4;
    float* pooled     = (float*)p; p += BATCH * DIM * 4;
    float* xT         = (float*)p; p += DIM * NROWS * 4;
    float* pm         = (float*)p; p += NROWS * CHUNKS * 4;
    float* ps         = (float*)p; p += NROWS * CHUNKS * 4;
    float* ptopv      = (float*)p; p += NROWS * CHUNKS * 8 * 4;
    int*   ptopi      = (int*)p;   p += NROWS * CHUNKS * 8 * 4;
    int*   alive_seq  = (int*)p;   p += NROWS * MAXLEN * 4;
    int*   fin_seq    = (int*)p;   p += NROWS * MAXLEN * 4;
    float* alive_lp   = (float*)p; p += NROWS * 4;
    float* fin_scores = (float*)p; p += NROWS * 4;
    int*   fin_flags  = (int*)p;   p += NROWS * 4;
    int*   batch_fin  = (int*)p;   p += BATCH * 4;

    k_pool<<<BATCH, DIM, 0, stream>>>(src, Esrc, pooled);
    k_init<<<1, 1024, 0, stream>>>(alive_seq, alive_lp, fin_seq, fin_scores, fin_flags, batch_fin);
    for (int t = 0; t < MAXLEN - 1; ++t) {
        k_x<<<NROWS, DIM, 0, stream>>>(Etgt, pooled, alive_seq, t, xT);
        k_gemm<<<dim3(VOCABSZ / 256, 4), 256, 0, stream>>>(xT, W, bias, logits);
        k_part<<<dim3(NROWS, CHUNKS), 256, 0, stream>>>(logits, pm, ps, ptopv, ptopi);
        k_mergesel<<<BATCH, 64, 0, stream>>>(pm, ps, ptopv, ptopi, alive_seq, alive_lp,
                                             fin_seq, fin_scores, fin_flags, batch_fin, t);
    }
    k_out<<<1, 256, 0, stream>>>(fin_seq, out);
}

// Round 4
// 1693.950 us; speedup vs baseline: 2.6718x; 1.7226x over previous
//
#include <hip/hip_runtime.h>
#include <math.h>

#define BATCH 16
#define SRCLEN 128
#define DIM 512
#define VOCABSZ 32000
#define BEAM 4
#define MAXLEN 16
#define NROWS (BATCH*BEAM)   // 64
#define BOS_TOK 1
#define EOS_TOK 2
#define NEGINF 1e9f
#define CHUNKS 8
#define CHUNK 4000           // VOCABSZ / CHUNKS

// ---------------- encoder pool: pooled[b][d] = masked mean of E_src[src[b,s]] ----------------
__global__ __launch_bounds__(512) void k_pool(const int* __restrict__ src,
                                              const float* __restrict__ Esrc,
                                              float* __restrict__ pooled) {
    int b = blockIdx.x;
    int d = threadIdx.x;
    float acc = 0.f, cnt = 0.f;
    for (int s = 0; s < SRCLEN; ++s) {
        int tok = src[b * SRCLEN + s];
        if (tok != 0) { acc += Esrc[(size_t)tok * DIM + d]; cnt += 1.f; }
    }
    pooled[b * DIM + d] = acc / fmaxf(cnt, 1.f);
}

// ---------------- state init ----------------
__global__ __launch_bounds__(1024) void k_init(int* __restrict__ alive_seq, float* __restrict__ alive_lp,
                                               int* __restrict__ fin_seq, float* __restrict__ fin_scores,
                                               int* __restrict__ fin_flags, int* __restrict__ batch_fin) {
    int tid = threadIdx.x;  // 1024 = NROWS*MAXLEN
    alive_seq[tid] = (tid % MAXLEN == 0) ? BOS_TOK : 0;
    fin_seq[tid] = 0;
    if (tid < NROWS) {
        alive_lp[tid] = (tid % BEAM == 0) ? 0.f : -INFINITY;
        fin_scores[tid] = -NEGINF;
        fin_flags[tid] = 0;
    }
    if (tid < BATCH) batch_fin[tid] = 0;
}

// ---------------- decoder input, grouped-transposed: xT[g][d][r] = E_tgt[last][d]+pooled ----------------
__global__ __launch_bounds__(512) void k_x(const float* __restrict__ Etgt,
                                           const float* __restrict__ pooled,
                                           const int* __restrict__ alive_seq, int t,
                                           float* __restrict__ xT) {
    int i = blockIdx.x;   // row 0..63
    int d = threadIdx.x;  // 0..511
    int last = alive_seq[i * MAXLEN + t];
    float v = Etgt[(size_t)last * DIM + d] + pooled[(i >> 2) * DIM + d];
    int g = i >> 4, r = i & 15;
    xT[(g * DIM + d) * 16 + r] = v;
}

// ---------------- logits GEMM: logits[r0+i][v] = sum_d x[d][i]*W[d][v] + b[v] ----------------
__global__ __launch_bounds__(256) void k_gemm(const float* __restrict__ xT,
                                              const float* __restrict__ W,
                                              const float* __restrict__ bias,
                                              float* __restrict__ logits) {
    int v = blockIdx.x * 256 + threadIdx.x;
    int g = blockIdx.y;
    const float* xg = xT + (size_t)g * DIM * 16;
    float acc[16];
#pragma unroll
    for (int i = 0; i < 16; ++i) acc[i] = 0.f;
    for (int d = 0; d < DIM; d += 4) {
        float w0 = W[(size_t)(d + 0) * VOCABSZ + v];
        float w1 = W[(size_t)(d + 1) * VOCABSZ + v];
        float w2 = W[(size_t)(d + 2) * VOCABSZ + v];
        float w3 = W[(size_t)(d + 3) * VOCABSZ + v];
        const float* x0 = xg + (d + 0) * 16;
        const float* x1 = xg + (d + 1) * 16;
        const float* x2 = xg + (d + 2) * 16;
        const float* x3 = xg + (d + 3) * 16;
#pragma unroll
        for (int i = 0; i < 16; ++i) acc[i] = fmaf(x0[i], w0, acc[i]);
#pragma unroll
        for (int i = 0; i < 16; ++i) acc[i] = fmaf(x1[i], w1, acc[i]);
#pragma unroll
        for (int i = 0; i < 16; ++i) acc[i] = fmaf(x2[i], w2, acc[i]);
#pragma unroll
        for (int i = 0; i < 16; ++i) acc[i] = fmaf(x3[i], w3, acc[i]);
    }
    float bb = bias[v];
    int r0 = g * 16;
#pragma unroll
    for (int i = 0; i < 16; ++i) logits[(size_t)(r0 + i) * VOCABSZ + v] = acc[i] + bb;
}

// ---------------- per-(row,chunk): partial max, sumexp, top-8 ----------------
__global__ __launch_bounds__(256) void k_part(const float* __restrict__ logits,
                                              float* __restrict__ pm, float* __restrict__ ps,
                                              float* __restrict__ ptopv, int* __restrict__ ptopi) {
    int row = blockIdx.x, ch = blockIdx.y;
    int tid = threadIdx.x;
    const float4* lr4 = (const float4*)(logits + (size_t)row * VOCABSZ + ch * CHUNK);

    float va[16]; int np = 0;
    float lv[8]; int li[8];
#pragma unroll
    for (int j = 0; j < 8; ++j) { lv[j] = -INFINITY; li[j] = 0x7FFFFFFF; }

#pragma unroll
    for (int j = 0; j < 4; ++j) {
        int idx = j * 256 + tid;
        if (idx < CHUNK / 4) {
            float4 q = lr4[idx];
            int gi = ch * CHUNK + idx * 4;
            float vals[4] = {q.x, q.y, q.z, q.w};
#pragma unroll
            for (int c = 0; c < 4; ++c) {
                float x = vals[c];
                va[np++] = x;
                int v = gi + c;
                if (x > lv[7] || (x == lv[7] && v < li[7])) {
                    lv[7] = x; li[7] = v;
#pragma unroll
                    for (int q2 = 7; q2 > 0; --q2) {
                        bool sw = (lv[q2] > lv[q2-1]) || (lv[q2] == lv[q2-1] && li[q2] < li[q2-1]);
                        if (sw) { float tv = lv[q2]; lv[q2] = lv[q2-1]; lv[q2-1] = tv;
                                  int  ti = li[q2]; li[q2] = li[q2-1]; li[q2-1] = ti; }
                    }
                }
            }
        }
    }

    // block max
    __shared__ float sred[256];
    float m_t = -INFINITY;
    for (int j = 0; j < np; ++j) m_t = fmaxf(m_t, va[j]);
    sred[tid] = m_t;
    __syncthreads();
    for (int s = 128; s > 0; s >>= 1) { if (tid < s) sred[tid] = fmaxf(sred[tid], sred[tid+s]); __syncthreads(); }
    float m = sred[0];
    __syncthreads();

    // block sumexp (values still in registers)
    float se = 0.f;
    for (int j = 0; j < np; ++j) se += expf(va[j] - m);
    sred[tid] = se;
    __syncthreads();
    for (int s = 128; s > 0; s >>= 1) { if (tid < s) sred[tid] += sred[tid+s]; __syncthreads(); }
    if (tid == 0) { pm[row * CHUNKS + ch] = m; ps[row * CHUNKS + ch] = sred[0]; }

    // merge per-thread top-8 -> block top-8 (value desc, index asc)
    __shared__ unsigned long long skey[256];
    int pos = 0;
    float* otv = ptopv + ((size_t)row * CHUNKS + ch) * 8;
    int*   oti = ptopi + ((size_t)row * CHUNKS + ch) * 8;
    for (int r = 0; r < 8; ++r) {
        unsigned long long mykey = 0ULL;
        if (pos < 8) {
            unsigned int fb = __float_as_uint(lv[pos]);
            fb = fb ^ ((fb >> 31) ? 0xFFFFFFFFu : 0x80000000u);
            mykey = ((unsigned long long)fb << 32) | (unsigned long long)(0xFFFFFFFFu - (unsigned int)li[pos]);
        }
        skey[tid] = mykey;
        __syncthreads();
        for (int s = 128; s > 0; s >>= 1) { if (tid < s) skey[tid] = (skey[tid] > skey[tid+s]) ? skey[tid] : skey[tid+s]; __syncthreads(); }
        unsigned long long best = skey[0];
        __syncthreads();
        if (mykey == best && mykey != 0ULL) {
            otv[r] = lv[pos];
            oti[r] = li[pos];
            pos++;
        }
        __syncthreads();
    }
}

// ---------------- key pack/unpack: (ordered float << 32) | (0xFFFFFFFF - id) ----------------
// max-key order == (value desc, id asc) == lax.top_k stable order; keys unique (ids unique).
__device__ inline unsigned long long packkey(float v, int idx) {
    unsigned int fb = __float_as_uint(v);
    fb = fb ^ ((fb >> 31) ? 0xFFFFFFFFu : 0x80000000u);
    return ((unsigned long long)fb << 32) | (unsigned long long)(0xFFFFFFFFu - (unsigned int)idx);
}
__device__ inline float unpack_val(unsigned long long k) {
    unsigned int fb = (unsigned int)(k >> 32);
    fb = fb ^ ((fb >> 31) ? 0x80000000u : 0xFFFFFFFFu);
    return __uint_as_float(fb);
}
__device__ inline int unpack_id(unsigned long long k) {
    return (int)(0xFFFFFFFFu - (unsigned int)(k & 0xFFFFFFFFu));
}
__device__ inline unsigned long long shflxor64(unsigned long long x, int mask) {
    unsigned int lo = (unsigned int)x, hi = (unsigned int)(x >> 32);
    lo = (unsigned int)__shfl_xor((int)lo, mask, 64);
    hi = (unsigned int)__shfl_xor((int)hi, mask, 64);
    return ((unsigned long long)hi << 32) | (unsigned long long)lo;
}
__device__ inline unsigned long long wavemax64(unsigned long long k) {
#pragma unroll
    for (int off = 1; off < 64; off <<= 1) {
        unsigned long long o = shflxor64(k, off);
        k = (o > k) ? o : k;
    }
    return k;
}

// ---------------- merge + beam bookkeeping, one block (one wave) per batch ----------------
// R3 fix: NO memory ops inside any selection loop. R2's serial LDS scans were
// latency-bound (4-way bank conflict + 120cyc ds_read x 512 dependent iters = 93us).
// Now: lane j holds candidate j of each row in registers, scores it exactly in
// reference op-order, packs a u64 key; top-8-of-256 (== ref's merged top-8, since
// score is monotone in logit within a row) via 8 rounds of 64-lane shfl butterfly
// max. Tiny top-4 selections run redundantly in all lanes on unrolled registers.
__global__ __launch_bounds__(64) void k_mergesel(const float* __restrict__ pm, const float* __restrict__ ps,
                                                 const float* __restrict__ ptopv, const int* __restrict__ ptopi,
                                                 int* __restrict__ alive_seq, float* __restrict__ alive_lp,
                                                 int* __restrict__ fin_seq, float* __restrict__ fin_scores,
                                                 int* __restrict__ fin_flags, int* __restrict__ batch_fin, int t) {
    int b = blockIdx.x;
    int tid = threadIdx.x;
    __shared__ int aseq_old[BEAM][MAXLEN]; __shared__ int fseq_old[BEAM][MAXLEN];
    __shared__ float s_tlp[8]; __shared__ int s_ttok[8], s_tbeam[8];
    __shared__ int s_aidx[4], s_fidx[4];
    __shared__ float s_nfsc[4]; __shared__ int s_nffl[4];
    float lpen = (float)(t + 1);

    // stage old sequences (cooperative; needed for gather-through-beam writes)
    { int k = tid >> 4, p = tid & 15;
      aseq_old[k][p] = alive_seq[(b * BEAM + k) * MAXLEN + p];
      fseq_old[k][p] = fin_seq[(b * BEAM + k) * MAXLEN + p]; }

    // per-lane candidate loads (coalesced: lane j -> entry j of each row)
    float rv[4]; int ri[4];
#pragma unroll
    for (int k = 0; k < 4; ++k) {
        rv[k] = ptopv[(size_t)(b * BEAM + k) * 64 + tid];
        ri[k] = ptopi[(size_t)(b * BEAM + k) * 64 + tid];
    }

    // wave-uniform loads (s_load path), redundantly in every lane
    float alp[4], fsc[4]; int ffl[4];
#pragma unroll
    for (int k = 0; k < 4; ++k) {
        alp[k] = alive_lp[b * BEAM + k];
        fsc[k] = fin_scores[b * BEAM + k];
        ffl[k] = fin_flags[b * BEAM + k];
    }
    int bf_old = batch_fin[b];

    // per-row m / log-sum-exp, exact R2 op order (c ascending), all lanes redundantly
    float srm[4], srl[4];
#pragma unroll
    for (int k = 0; k < 4; ++k) {
        float m = -INFINITY;
#pragma unroll
        for (int c = 0; c < CHUNKS; ++c) m = fmaxf(m, pm[(b * BEAM + k) * CHUNKS + c]);
        float s = 0.f;
#pragma unroll
        for (int c = 0; c < CHUNKS; ++c) s += ps[(b * BEAM + k) * CHUNKS + c] * expf(pm[(b * BEAM + k) * CHUNKS + c] - m);
        srm[k] = m; srl[k] = logf(s);
    }

    // score each candidate in exact reference op order, pack keys
    unsigned long long key[4];
#pragma unroll
    for (int k = 0; k < 4; ++k) {
        float sh = rv[k] - srm[k];
        float lp = sh - srl[k];
        float full = alp[k] + lp;
        float cv = full / lpen;
        key[k] = packkey(cv, k * VOCABSZ + ri[k]);
    }
    // sort 4 keys descending (network: (0,1)(2,3)(0,2)(1,3)(1,2))
    {
        unsigned long long tmp;
#define CSW(a,b) if (key[b] > key[a]) { tmp = key[a]; key[a] = key[b]; key[b] = tmp; }
        CSW(0,1) CSW(2,3) CSW(0,2) CSW(1,3) CSW(1,2)
#undef CSW
    }

    // extract global top-8 of 256: 8 rounds of 64-lane butterfly max over lane heads
    float tscore[8], tlp[8]; int ttok[8], tbeam[8], tfin[8];
    int pos = 0;
#pragma unroll
    for (int r = 0; r < 8; ++r) {
        unsigned long long head = (pos == 0) ? key[0] : (pos == 1) ? key[1] :
                                  (pos == 2) ? key[2] : (pos == 3) ? key[3] : 0ULL;
        unsigned long long mx = wavemax64(head);
        if (head == mx && head != 0ULL) pos++;   // unique keys -> exactly one owner
        float sc = unpack_val(mx);
        int id = unpack_id(mx);
        tscore[r] = sc;
        tlp[r] = sc * lpen;                      // match reference rounding
        ttok[r] = id % VOCABSZ;
        tbeam[r] = id / VOCABSZ;
        tfin[r] = (ttok[r] == EOS_TOK) ? 1 : 0;
    }

    // alive selection: top-4 of curr (value desc, position asc) — registers, all lanes
    int aidx[4];
    {
        float curr[8];
#pragma unroll
        for (int j = 0; j < 8; ++j) curr[j] = tscore[j] + (tfin[j] ? -NEGINF : 0.0f);
        unsigned int used = 0;
#pragma unroll
        for (int r = 0; r < 4; ++r) {
            float bv = 0.f; int bj = -1;
#pragma unroll
            for (int j = 0; j < 8; ++j) {
                bool skip = (used >> j) & 1u;
                bool better = !skip && (bj < 0 || curr[j] > bv);
                if (better) { bv = curr[j]; bj = j; }
            }
            used |= 1u << bj; aidx[r] = bj;
        }
    }
    // finished selection: cand = [old fin (4), fs (8)], top-4 (value desc, position asc)
    int fidx[4]; float nfsc[4]; int nffl[4];
    {
        float fscand[12]; int fflcand[12];
#pragma unroll
        for (int j = 0; j < 4; ++j) { fscand[j] = fsc[j]; fflcand[j] = ffl[j]; }
#pragma unroll
        for (int q = 0; q < 8; ++q) {
            float t1 = tscore[q] + (tfin[q] ? 0.0f : -NEGINF);
            float t2 = t1 + (bf_old ? -NEGINF : 0.0f);
            fscand[4 + q] = t2; fflcand[4 + q] = tfin[q];
        }
        unsigned int used = 0;
#pragma unroll
        for (int r = 0; r < 4; ++r) {
            float bv = 0.f; int bj = -1;
#pragma unroll
            for (int j = 0; j < 12; ++j) {
                bool skip = (used >> j) & 1u;
                bool better = !skip && (bj < 0 || fscand[j] > bv);
                if (better) { bv = fscand[j]; bj = j; }
            }
            used |= 1u << bj; fidx[r] = bj;
            nfsc[r] = bv; nffl[r] = fflcand[bj] != 0;
        }
        // fflcand[bj] dynamic index -> rebuild via select chain
#pragma unroll
        for (int r = 0; r < 4; ++r) {
            int bj = fidx[r]; int fl = 0;
#pragma unroll
            for (int j = 0; j < 12; ++j) if (bj == j) fl = fflcand[j];
            nffl[r] = fl;
        }
    }

    // publish small arrays to LDS for the dynamic-indexed write stage (single wave)
    if (tid == 0) {
#pragma unroll
        for (int r = 0; r < 8; ++r) { s_tlp[r] = tlp[r]; s_ttok[r] = ttok[r]; s_tbeam[r] = tbeam[r]; }
#pragma unroll
        for (int r = 0; r < 4; ++r) { s_aidx[r] = aidx[r]; s_fidx[r] = fidx[r]; s_nfsc[r] = nfsc[r]; s_nffl[r] = nffl[r]; }
    }
    __syncthreads();

    // write new sequences (gather from OLD alive_seq through tbeam, set token at t+1)
    { int k = tid >> 4, p = tid & 15;
      int j = s_aidx[k];
      int val = (p == t + 1) ? s_ttok[j] : aseq_old[s_tbeam[j]][p];
      alive_seq[(b * BEAM + k) * MAXLEN + p] = val;
      int fi = s_fidx[k]; int fval;
      if (fi < 4) fval = fseq_old[fi][p];
      else { int q = fi - 4; fval = (p == t + 1) ? s_ttok[q] : aseq_old[s_tbeam[q]][p]; }
      fin_seq[(b * BEAM + k) * MAXLEN + p] = fval; }

    if (tid < 4) {
        alive_lp[b * BEAM + tid] = s_tlp[s_aidx[tid]];
        fin_scores[b * BEAM + tid] = s_nfsc[tid];
        fin_flags[b * BEAM + tid] = s_nffl[tid];
    }
    if (tid == 0) {
        float lb = s_tlp[s_aidx[0]] / lpen;
        float lowest = nfsc[0] * (nffl[0] ? 1.f : 0.f);
        int allf = nffl[0];
#pragma unroll
        for (int k2 = 1; k2 < 4; ++k2) {
            float pz = nfsc[k2] * (nffl[k2] ? 1.f : 0.f);
            lowest = fminf(lowest, pz);
            allf = allf && nffl[k2];
        }
        lowest = lowest + (allf ? 0.f : -NEGINF);
        batch_fin[b] = bf_old || (lowest >= lb);
    }
}

// ---------------- output: fin_seq[:,0,:] as float ----------------
__global__ __launch_bounds__(256) void k_out(const int* __restrict__ fin_seq, float* __restrict__ out) {
    int tid = threadIdx.x;
    if (tid < BATCH * MAXLEN) {
        int b = tid / MAXLEN, p = tid % MAXLEN;
        out[tid] = (float)fin_seq[(b * BEAM + 0) * MAXLEN + p];
    }
}

extern "C" void kernel_launch(void* const* d_in, const int* in_sizes, int n_in,
                              void* d_out, int out_size, void* d_ws, size_t ws_size,
                              hipStream_t stream) {
    const int*   src  = (const int*)d_in[0];
    const float* Esrc = (const float*)d_in[1];
    const float* Etgt = (const float*)d_in[2];
    const float* W    = (const float*)d_in[3];
    const float* bias = (const float*)d_in[4];
    float* out = (float*)d_out;

    char* p = (char*)d_ws;
    float* logits     = (float*)p; p += (size_t)NROWS * VOCABSZ * 4;
    float* pooled     = (float*)p; p += BATCH * DIM * 4;
    float* xT         = (float*)p; p += DIM * NROWS * 4;
    float* pm         = (float*)p; p += NROWS * CHUNKS * 4;
    float* ps         = (float*)p; p += NROWS * CHUNKS * 4;
    float* ptopv      = (float*)p; p += NROWS * CHUNKS * 8 * 4;
    int*   ptopi      = (int*)p;   p += NROWS * CHUNKS * 8 * 4;
    int*   alive_seq  = (int*)p;   p += NROWS * MAXLEN * 4;
    int*   fin_seq    = (int*)p;   p += NROWS * MAXLEN * 4;
    float* alive_lp   = (float*)p; p += NROWS * 4;
    float* fin_scores = (float*)p; p += NROWS * 4;
    int*   fin_flags  = (int*)p;   p += NROWS * 4;
    int*   batch_fin  = (int*)p;   p += BATCH * 4;

    k_pool<<<BATCH, DIM, 0, stream>>>(src, Esrc, pooled);
    k_init<<<1, 1024, 0, stream>>>(alive_seq, alive_lp, fin_seq, fin_scores, fin_flags, batch_fin);
    for (int t = 0; t < MAXLEN - 1; ++t) {
        k_x<<<NROWS, DIM, 0, stream>>>(Etgt, pooled, alive_seq, t, xT);
        k_gemm<<<dim3(VOCABSZ / 256, 4), 256, 0, stream>>>(xT, W, bias, logits);
        k_part<<<dim3(NROWS, CHUNKS), 256, 0, stream>>>(logits, pm, ps, ptopv, ptopi);
        k_mergesel<<<BATCH, 64, 0, stream>>>(pm, ps, ptopv, ptopi, alive_seq, alive_lp,
                                             fin_seq, fin_scores, fin_flags, batch_fin, t);
    }
    k_out<<<1, 256, 0, stream>>>(fin_seq, out);
}

// Round 5
// 1626.451 us; speedup vs baseline: 2.7827x; 1.0415x over previous
//
#include <hip/hip_runtime.h>
#include <math.h>

#define BATCH 16
#define SRCLEN 128
#define DIM 512
#define VOCABSZ 32000
#define BEAM 4
#define MAXLEN 16
#define NROWS (BATCH*BEAM)   // 64
#define BOS_TOK 1
#define EOS_TOK 2
#define NEGINF 1e9f
#define CHUNKS 8
#define CHUNK 4000           // VOCABSZ / CHUNKS

// ---------------- encoder pool: pooled[b][d] = masked mean of E_src[src[b,s]] ----------------
__global__ __launch_bounds__(512) void k_pool(const int* __restrict__ src,
                                              const float* __restrict__ Esrc,
                                              float* __restrict__ pooled) {
    int b = blockIdx.x;
    int d = threadIdx.x;
    float acc = 0.f, cnt = 0.f;
    for (int s = 0; s < SRCLEN; ++s) {
        int tok = src[b * SRCLEN + s];
        if (tok != 0) { acc += Esrc[(size_t)tok * DIM + d]; cnt += 1.f; }
    }
    pooled[b * DIM + d] = acc / fmaxf(cnt, 1.f);
}

// ---------------- state init ----------------
__global__ __launch_bounds__(1024) void k_init(int* __restrict__ alive_seq, float* __restrict__ alive_lp,
                                               int* __restrict__ fin_seq, float* __restrict__ fin_scores,
                                               int* __restrict__ fin_flags, int* __restrict__ batch_fin) {
    int tid = threadIdx.x;  // 1024 = NROWS*MAXLEN
    alive_seq[tid] = (tid % MAXLEN == 0) ? BOS_TOK : 0;
    fin_seq[tid] = 0;
    if (tid < NROWS) {
        alive_lp[tid] = (tid % BEAM == 0) ? 0.f : -INFINITY;
        fin_scores[tid] = -NEGINF;
        fin_flags[tid] = 0;
    }
    if (tid < BATCH) batch_fin[tid] = 0;
}

// ---------------- decoder input, transposed: xT[d][i] = E_tgt[last_i][d] + pooled[i/4][d] ----------------
__global__ __launch_bounds__(512) void k_x(const float* __restrict__ Etgt,
                                           const float* __restrict__ pooled,
                                           const int* __restrict__ alive_seq, int t,
                                           float* __restrict__ xT) {
    int i = blockIdx.x;   // row 0..63
    int d = threadIdx.x;  // 0..511
    int last = alive_seq[i * MAXLEN + t];
    float v = Etgt[(size_t)last * DIM + d] + pooled[(i >> 2) * DIM + d];
    xT[d * NROWS + i] = v;
}

// ---------------- logits GEMM, split-K: partial[z][i][v] = sum_{d in z-slab} xT[d][i]*W[d][v] ----------------
// R4 restructure: y=1 (all 64 rows per block -> W fetched ~once: FETCH 129->~70MB),
// split-K=DIM/DLEN recovers blocks (125*NZ). Per d-iter: 1 W load per 128 FMA-cycles
// (was 4 loads per 128) -> latency covered; 2-deep manual unroll keeps loads in flight.
template<int DLEN>
__global__ __launch_bounds__(256) void k_gemm2(const float* __restrict__ xT,
                                               const float* __restrict__ W,
                                               float* __restrict__ partial) {
    int v = blockIdx.x * 256 + threadIdx.x;
    int z = blockIdx.z;
    int d0 = z * DLEN;
    float acc[NROWS];
#pragma unroll
    for (int i = 0; i < NROWS; ++i) acc[i] = 0.f;
    const float* wp = W + (size_t)d0 * VOCABSZ + v;
    const float* xp = xT + (size_t)d0 * NROWS;
    for (int dd = 0; dd < DLEN; dd += 2) {
        float w0 = wp[0];
        float w1 = wp[VOCABSZ];
        wp += 2 * VOCABSZ;
        const float* x0 = xp;
        const float* x1 = xp + NROWS;
        xp += 2 * NROWS;
#pragma unroll
        for (int i = 0; i < NROWS; ++i) acc[i] = fmaf(x0[i], w0, acc[i]);
#pragma unroll
        for (int i = 0; i < NROWS; ++i) acc[i] = fmaf(x1[i], w1, acc[i]);
    }
    float* op = partial + (size_t)z * NROWS * VOCABSZ + v;
#pragma unroll
    for (int i = 0; i < NROWS; ++i) op[(size_t)i * VOCABSZ] = acc[i];
}

// ---------------- per-(row,chunk): partial max, sumexp, top-8 (sums NZ split-K slabs + bias) ----------------
template<int NZ>
__global__ __launch_bounds__(256) void k_part(const float* __restrict__ partial,
                                              const float* __restrict__ bias,
                                              float* __restrict__ pm, float* __restrict__ ps,
                                              float* __restrict__ ptopv, int* __restrict__ ptopi) {
    int row = blockIdx.x, ch = blockIdx.y;
    int tid = threadIdx.x;
    const size_t slab = (size_t)NROWS * VOCABSZ;
    const float4* lr4[NZ];
#pragma unroll
    for (int zz = 0; zz < NZ; ++zz)
        lr4[zz] = (const float4*)(partial + slab * zz + (size_t)row * VOCABSZ + ch * CHUNK);
    const float4* b4 = (const float4*)(bias + ch * CHUNK);

    float va[16]; int np = 0;
    float lv[8]; int li[8];
#pragma unroll
    for (int j = 0; j < 8; ++j) { lv[j] = -INFINITY; li[j] = 0x7FFFFFFF; }

#pragma unroll
    for (int j = 0; j < 4; ++j) {
        int idx = j * 256 + tid;
        if (idx < CHUNK / 4) {
            float4 q = lr4[0][idx];
#pragma unroll
            for (int zz = 1; zz < NZ; ++zz) {
                float4 q2 = lr4[zz][idx];
                q.x += q2.x; q.y += q2.y; q.z += q2.z; q.w += q2.w;
            }
            float4 bb = b4[idx];
            q.x += bb.x; q.y += bb.y; q.z += bb.z; q.w += bb.w;
            int gi = ch * CHUNK + idx * 4;
            float vals[4] = {q.x, q.y, q.z, q.w};
#pragma unroll
            for (int c = 0; c < 4; ++c) {
                float x = vals[c];
                va[np++] = x;
                int v = gi + c;
                if (x > lv[7] || (x == lv[7] && v < li[7])) {
                    lv[7] = x; li[7] = v;
#pragma unroll
                    for (int q2 = 7; q2 > 0; --q2) {
                        bool sw = (lv[q2] > lv[q2-1]) || (lv[q2] == lv[q2-1] && li[q2] < li[q2-1]);
                        if (sw) { float tv = lv[q2]; lv[q2] = lv[q2-1]; lv[q2-1] = tv;
                                  int  ti = li[q2]; li[q2] = li[q2-1]; li[q2-1] = ti; }
                    }
                }
            }
        }
    }

    // block max
    __shared__ float sred[256];
    float m_t = -INFINITY;
    for (int j = 0; j < np; ++j) m_t = fmaxf(m_t, va[j]);
    sred[tid] = m_t;
    __syncthreads();
    for (int s = 128; s > 0; s >>= 1) { if (tid < s) sred[tid] = fmaxf(sred[tid], sred[tid+s]); __syncthreads(); }
    float m = sred[0];
    __syncthreads();

    // block sumexp (values still in registers)
    float se = 0.f;
    for (int j = 0; j < np; ++j) se += expf(va[j] - m);
    sred[tid] = se;
    __syncthreads();
    for (int s = 128; s > 0; s >>= 1) { if (tid < s) sred[tid] += sred[tid+s]; __syncthreads(); }
    if (tid == 0) { pm[row * CHUNKS + ch] = m; ps[row * CHUNKS + ch] = sred[0]; }

    // merge per-thread top-8 -> block top-8 (value desc, index asc)
    __shared__ unsigned long long skey[256];
    int pos = 0;
    float* otv = ptopv + ((size_t)row * CHUNKS + ch) * 8;
    int*   oti = ptopi + ((size_t)row * CHUNKS + ch) * 8;
    for (int r = 0; r < 8; ++r) {
        unsigned long long mykey = 0ULL;
        if (pos < 8) {
            unsigned int fb = __float_as_uint(lv[pos]);
            fb = fb ^ ((fb >> 31) ? 0xFFFFFFFFu : 0x80000000u);
            mykey = ((unsigned long long)fb << 32) | (unsigned long long)(0xFFFFFFFFu - (unsigned int)li[pos]);
        }
        skey[tid] = mykey;
        __syncthreads();
        for (int s = 128; s > 0; s >>= 1) { if (tid < s) skey[tid] = (skey[tid] > skey[tid+s]) ? skey[tid] : skey[tid+s]; __syncthreads(); }
        unsigned long long best = skey[0];
        __syncthreads();
        if (mykey == best && mykey != 0ULL) {
            otv[r] = lv[pos];
            oti[r] = li[pos];
            pos++;
        }
        __syncthreads();
    }
}

// ---------------- key pack/unpack: (ordered float << 32) | (0xFFFFFFFF - id) ----------------
__device__ inline unsigned long long packkey(float v, int idx) {
    unsigned int fb = __float_as_uint(v);
    fb = fb ^ ((fb >> 31) ? 0xFFFFFFFFu : 0x80000000u);
    return ((unsigned long long)fb << 32) | (unsigned long long)(0xFFFFFFFFu - (unsigned int)idx);
}
__device__ inline float unpack_val(unsigned long long k) {
    unsigned int fb = (unsigned int)(k >> 32);
    fb = fb ^ ((fb >> 31) ? 0x80000000u : 0xFFFFFFFFu);
    return __uint_as_float(fb);
}
__device__ inline int unpack_id(unsigned long long k) {
    return (int)(0xFFFFFFFFu - (unsigned int)(k & 0xFFFFFFFFu));
}
__device__ inline unsigned long long shflxor64(unsigned long long x, int mask) {
    unsigned int lo = (unsigned int)x, hi = (unsigned int)(x >> 32);
    lo = (unsigned int)__shfl_xor((int)lo, mask, 64);
    hi = (unsigned int)__shfl_xor((int)hi, mask, 64);
    return ((unsigned long long)hi << 32) | (unsigned long long)lo;
}
__device__ inline unsigned long long wavemax64(unsigned long long k) {
#pragma unroll
    for (int off = 1; off < 64; off <<= 1) {
        unsigned long long o = shflxor64(k, off);
        k = (o > k) ? o : k;
    }
    return k;
}

// ---------------- merge + beam bookkeeping, one block (one wave) per batch ----------------
__global__ __launch_bounds__(64) void k_mergesel(const float* __restrict__ pm, const float* __restrict__ ps,
                                                 const float* __restrict__ ptopv, const int* __restrict__ ptopi,
                                                 int* __restrict__ alive_seq, float* __restrict__ alive_lp,
                                                 int* __restrict__ fin_seq, float* __restrict__ fin_scores,
                                                 int* __restrict__ fin_flags, int* __restrict__ batch_fin, int t) {
    int b = blockIdx.x;
    int tid = threadIdx.x;
    __shared__ int aseq_old[BEAM][MAXLEN]; __shared__ int fseq_old[BEAM][MAXLEN];
    __shared__ float s_tlp[8]; __shared__ int s_ttok[8], s_tbeam[8];
    __shared__ int s_aidx[4], s_fidx[4];
    __shared__ float s_nfsc[4]; __shared__ int s_nffl[4];
    float lpen = (float)(t + 1);

    { int k = tid >> 4, p = tid & 15;
      aseq_old[k][p] = alive_seq[(b * BEAM + k) * MAXLEN + p];
      fseq_old[k][p] = fin_seq[(b * BEAM + k) * MAXLEN + p]; }

    float rv[4]; int ri[4];
#pragma unroll
    for (int k = 0; k < 4; ++k) {
        rv[k] = ptopv[(size_t)(b * BEAM + k) * 64 + tid];
        ri[k] = ptopi[(size_t)(b * BEAM + k) * 64 + tid];
    }

    float alp[4], fsc[4]; int ffl[4];
#pragma unroll
    for (int k = 0; k < 4; ++k) {
        alp[k] = alive_lp[b * BEAM + k];
        fsc[k] = fin_scores[b * BEAM + k];
        ffl[k] = fin_flags[b * BEAM + k];
    }
    int bf_old = batch_fin[b];

    float srm[4], srl[4];
#pragma unroll
    for (int k = 0; k < 4; ++k) {
        float m = -INFINITY;
#pragma unroll
        for (int c = 0; c < CHUNKS; ++c) m = fmaxf(m, pm[(b * BEAM + k) * CHUNKS + c]);
        float s = 0.f;
#pragma unroll
        for (int c = 0; c < CHUNKS; ++c) s += ps[(b * BEAM + k) * CHUNKS + c] * expf(pm[(b * BEAM + k) * CHUNKS + c] - m);
        srm[k] = m; srl[k] = logf(s);
    }

    unsigned long long key[4];
#pragma unroll
    for (int k = 0; k < 4; ++k) {
        float sh = rv[k] - srm[k];
        float lp = sh - srl[k];
        float full = alp[k] + lp;
        float cv = full / lpen;
        key[k] = packkey(cv, k * VOCABSZ + ri[k]);
    }
    {
        unsigned long long tmp;
#define CSW(a,b) if (key[b] > key[a]) { tmp = key[a]; key[a] = key[b]; key[b] = tmp; }
        CSW(0,1) CSW(2,3) CSW(0,2) CSW(1,3) CSW(1,2)
#undef CSW
    }

    float tscore[8], tlp[8]; int ttok[8], tbeam[8], tfin[8];
    int pos = 0;
#pragma unroll
    for (int r = 0; r < 8; ++r) {
        unsigned long long head = (pos == 0) ? key[0] : (pos == 1) ? key[1] :
                                  (pos == 2) ? key[2] : (pos == 3) ? key[3] : 0ULL;
        unsigned long long mx = wavemax64(head);
        if (head == mx && head != 0ULL) pos++;
        float sc = unpack_val(mx);
        int id = unpack_id(mx);
        tscore[r] = sc;
        tlp[r] = sc * lpen;
        ttok[r] = id % VOCABSZ;
        tbeam[r] = id / VOCABSZ;
        tfin[r] = (ttok[r] == EOS_TOK) ? 1 : 0;
    }

    int aidx[4];
    {
        float curr[8];
#pragma unroll
        for (int j = 0; j < 8; ++j) curr[j] = tscore[j] + (tfin[j] ? -NEGINF : 0.0f);
        unsigned int used = 0;
#pragma unroll
        for (int r = 0; r < 4; ++r) {
            float bv = 0.f; int bj = -1;
#pragma unroll
            for (int j = 0; j < 8; ++j) {
                bool skip = (used >> j) & 1u;
                bool better = !skip && (bj < 0 || curr[j] > bv);
                if (better) { bv = curr[j]; bj = j; }
            }
            used |= 1u << bj; aidx[r] = bj;
        }
    }
    int fidx[4]; float nfsc[4]; int nffl[4];
    {
        float fscand[12]; int fflcand[12];
#pragma unroll
        for (int j = 0; j < 4; ++j) { fscand[j] = fsc[j]; fflcand[j] = ffl[j]; }
#pragma unroll
        for (int q = 0; q < 8; ++q) {
            float t1 = tscore[q] + (tfin[q] ? 0.0f : -NEGINF);
            float t2 = t1 + (bf_old ? -NEGINF : 0.0f);
            fscand[4 + q] = t2; fflcand[4 + q] = tfin[q];
        }
        unsigned int used = 0;
#pragma unroll
        for (int r = 0; r < 4; ++r) {
            float bv = 0.f; int bj = -1;
#pragma unroll
            for (int j = 0; j < 12; ++j) {
                bool skip = (used >> j) & 1u;
                bool better = !skip && (bj < 0 || fscand[j] > bv);
                if (better) { bv = fscand[j]; bj = j; }
            }
            used |= 1u << bj; fidx[r] = bj;
            nfsc[r] = bv;
        }
#pragma unroll
        for (int r = 0; r < 4; ++r) {
            int bj = fidx[r]; int fl = 0;
#pragma unroll
            for (int j = 0; j < 12; ++j) if (bj == j) fl = fflcand[j];
            nffl[r] = fl;
        }
    }

    if (tid == 0) {
#pragma unroll
        for (int r = 0; r < 8; ++r) { s_tlp[r] = tlp[r]; s_ttok[r] = ttok[r]; s_tbeam[r] = tbeam[r]; }
#pragma unroll
        for (int r = 0; r < 4; ++r) { s_aidx[r] = aidx[r]; s_fidx[r] = fidx[r]; s_nfsc[r] = nfsc[r]; s_nffl[r] = nffl[r]; }
    }
    __syncthreads();

    { int k = tid >> 4, p = tid & 15;
      int j = s_aidx[k];
      int val = (p == t + 1) ? s_ttok[j] : aseq_old[s_tbeam[j]][p];
      alive_seq[(b * BEAM + k) * MAXLEN + p] = val;
      int fi = s_fidx[k]; int fval;
      if (fi < 4) fval = fseq_old[fi][p];
      else { int q = fi - 4; fval = (p == t + 1) ? s_ttok[q] : aseq_old[s_tbeam[q]][p]; }
      fin_seq[(b * BEAM + k) * MAXLEN + p] = fval; }

    if (tid < 4) {
        alive_lp[b * BEAM + tid] = s_tlp[s_aidx[tid]];
        fin_scores[b * BEAM + tid] = s_nfsc[tid];
        fin_flags[b * BEAM + tid] = s_nffl[tid];
    }
    if (tid == 0) {
        float lb = s_tlp[s_aidx[0]] / lpen;
        float lowest = nfsc[0] * (nffl[0] ? 1.f : 0.f);
        int allf = nffl[0];
#pragma unroll
        for (int k2 = 1; k2 < 4; ++k2) {
            float pz = nfsc[k2] * (nffl[k2] ? 1.f : 0.f);
            lowest = fminf(lowest, pz);
            allf = allf && nffl[k2];
        }
        lowest = lowest + (allf ? 0.f : -NEGINF);
        batch_fin[b] = bf_old || (lowest >= lb);
    }
}

// ---------------- output: fin_seq[:,0,:] as float ----------------
__global__ __launch_bounds__(256) void k_out(const int* __restrict__ fin_seq, float* __restrict__ out) {
    int tid = threadIdx.x;
    if (tid < BATCH * MAXLEN) {
        int b = tid / MAXLEN, p = tid % MAXLEN;
        out[tid] = (float)fin_seq[(b * BEAM + 0) * MAXLEN + p];
    }
}

extern "C" void kernel_launch(void* const* d_in, const int* in_sizes, int n_in,
                              void* d_out, int out_size, void* d_ws, size_t ws_size,
                              hipStream_t stream) {
    const int*   src  = (const int*)d_in[0];
    const float* Esrc = (const float*)d_in[1];
    const float* Etgt = (const float*)d_in[2];
    const float* W    = (const float*)d_in[3];
    const float* bias = (const float*)d_in[4];
    float* out = (float*)d_out;

    const size_t slab = (size_t)NROWS * VOCABSZ * 4;  // 8.192 MB
    // choose split-K by available scratch: 4 slabs + ~0.3 MB aux
    const bool big = ws_size >= 4 * slab + (1u << 20);
    const int NZ = big ? 4 : 1;

    char* p = (char*)d_ws;
    float* partial    = (float*)p; p += NZ * slab;
    float* pooled     = (float*)p; p += BATCH * DIM * 4;
    float* xT         = (float*)p; p += DIM * NROWS * 4;
    float* pm         = (float*)p; p += NROWS * CHUNKS * 4;
    float* ps         = (float*)p; p += NROWS * CHUNKS * 4;
    float* ptopv      = (float*)p; p += NROWS * CHUNKS * 8 * 4;
    int*   ptopi      = (int*)p;   p += NROWS * CHUNKS * 8 * 4;
    int*   alive_seq  = (int*)p;   p += NROWS * MAXLEN * 4;
    int*   fin_seq    = (int*)p;   p += NROWS * MAXLEN * 4;
    float* alive_lp   = (float*)p; p += NROWS * 4;
    float* fin_scores = (float*)p; p += NROWS * 4;
    int*   fin_flags  = (int*)p;   p += NROWS * 4;
    int*   batch_fin  = (int*)p;   p += BATCH * 4;

    k_pool<<<BATCH, DIM, 0, stream>>>(src, Esrc, pooled);
    k_init<<<1, 1024, 0, stream>>>(alive_seq, alive_lp, fin_seq, fin_scores, fin_flags, batch_fin);
    for (int t = 0; t < MAXLEN - 1; ++t) {
        k_x<<<NROWS, DIM, 0, stream>>>(Etgt, pooled, alive_seq, t, xT);
        if (big) {
            k_gemm2<DIM/4><<<dim3(VOCABSZ / 256, 1, 4), 256, 0, stream>>>(xT, W, partial);
            k_part<4><<<dim3(NROWS, CHUNKS), 256, 0, stream>>>(partial, bias, pm, ps, ptopv, ptopi);
        } else {
            k_gemm2<DIM><<<dim3(VOCABSZ / 256, 1, 1), 256, 0, stream>>>(xT, W, partial);
            k_part<1><<<dim3(NROWS, CHUNKS), 256, 0, stream>>>(partial, bias, pm, ps, ptopv, ptopi);
        }
        k_mergesel<<<BATCH, 64, 0, stream>>>(pm, ps, ptopv, ptopi, alive_seq, alive_lp,
                                             fin_seq, fin_scores, fin_flags, batch_fin, t);
    }
    k_out<<<1, 256, 0, stream>>>(fin_seq, out);
}

// Round 6
// 1301.507 us; speedup vs baseline: 3.4774x; 1.2497x over previous
//
#include <hip/hip_runtime.h>
#include <math.h>

#define BATCH 16
#define SRCLEN 128
#define DIM 512
#define VOCABSZ 32000
#define BEAM 4
#define MAXLEN 16
#define NROWS (BATCH*BEAM)   // 64
#define BOS_TOK 1
#define EOS_TOK 2
#define NEGINF 1e9f
#define CHUNKS 8
#define CHUNK 4000           // VOCABSZ / CHUNKS

// ---------------- encoder pool: pooled[b][d] = masked mean of E_src[src[b,s]] ----------------
__global__ __launch_bounds__(512) void k_pool(const int* __restrict__ src,
                                              const float* __restrict__ Esrc,
                                              float* __restrict__ pooled) {
    int b = blockIdx.x;
    int d = threadIdx.x;
    float acc = 0.f, cnt = 0.f;
    for (int s = 0; s < SRCLEN; ++s) {
        int tok = src[b * SRCLEN + s];
        if (tok != 0) { acc += Esrc[(size_t)tok * DIM + d]; cnt += 1.f; }
    }
    pooled[b * DIM + d] = acc / fmaxf(cnt, 1.f);
}

// ---------------- state init ----------------
__global__ __launch_bounds__(1024) void k_init(int* __restrict__ alive_seq, float* __restrict__ alive_lp,
                                               int* __restrict__ fin_seq, float* __restrict__ fin_scores,
                                               int* __restrict__ fin_flags, int* __restrict__ batch_fin) {
    int tid = threadIdx.x;  // 1024 = NROWS*MAXLEN
    alive_seq[tid] = (tid % MAXLEN == 0) ? BOS_TOK : 0;
    fin_seq[tid] = 0;
    if (tid < NROWS) {
        alive_lp[tid] = (tid % BEAM == 0) ? 0.f : -INFINITY;
        fin_scores[tid] = -NEGINF;
        fin_flags[tid] = 0;
    }
    if (tid < BATCH) batch_fin[tid] = 0;
}

// ---------------- decoder input, transposed: xT[d][i] = E_tgt[last_i][d] + pooled[i/4][d] ----------------
__global__ __launch_bounds__(512) void k_x(const float* __restrict__ Etgt,
                                           const float* __restrict__ pooled,
                                           const int* __restrict__ alive_seq, int t,
                                           float* __restrict__ xT) {
    int i = blockIdx.x;   // row 0..63
    int d = threadIdx.x;  // 0..511
    int last = alive_seq[i * MAXLEN + t];
    float v = Etgt[(size_t)last * DIM + d] + pooled[(i >> 2) * DIM + d];
    xT[d * NROWS + i] = v;
}

// ---------------- logits GEMM, split-K, register-safe tiling ----------------
// R5 post-mortem: acc[64] spilled to scratch (VGPR_Count=36!) -> every FMA had a
// scratch round-trip; VALUBusy stuck at 17%. R6: 128v x 64row tile per block,
// thread = 1 v x 32 rows -> acc[32] stays in registers (~50 VGPR). Row-half
// (tid>>7) is wave-uniform; readfirstlane forces it scalar so x reads stay on
// the s_load path (from threadIdx the compiler assumes divergent -> VMEM).
// Grid 250 x z: 1000 blocks -> ~4 waves/SIMD. FMA order: d ascending per slab,
// bit-identical to R5's passing numerics.
template<int DLEN>
__global__ __launch_bounds__(256) void k_gemm3(const float* __restrict__ xT,
                                               const float* __restrict__ W,
                                               float* __restrict__ partial) {
    int v  = blockIdx.x * 128 + (threadIdx.x & 127);
    int rh = __builtin_amdgcn_readfirstlane(threadIdx.x >> 7);  // wave-uniform row half
    int r0 = rh * 32;
    int z  = blockIdx.z;
    int d0 = z * DLEN;
    float acc[32];
#pragma unroll
    for (int i = 0; i < 32; ++i) acc[i] = 0.f;
    const float* wp = W + (size_t)d0 * VOCABSZ + v;
    const float* xp = xT + (size_t)d0 * NROWS + r0;
    for (int dd = 0; dd < DLEN; dd += 4) {
        float w0 = wp[0];
        float w1 = wp[(size_t)VOCABSZ];
        float w2 = wp[(size_t)2 * VOCABSZ];
        float w3 = wp[(size_t)3 * VOCABSZ];
        wp += (size_t)4 * VOCABSZ;
        const float* x0 = xp;
        const float* x1 = xp + NROWS;
        const float* x2 = xp + 2 * NROWS;
        const float* x3 = xp + 3 * NROWS;
        xp += 4 * NROWS;
#pragma unroll
        for (int i = 0; i < 32; ++i) acc[i] = fmaf(x0[i], w0, acc[i]);
#pragma unroll
        for (int i = 0; i < 32; ++i) acc[i] = fmaf(x1[i], w1, acc[i]);
#pragma unroll
        for (int i = 0; i < 32; ++i) acc[i] = fmaf(x2[i], w2, acc[i]);
#pragma unroll
        for (int i = 0; i < 32; ++i) acc[i] = fmaf(x3[i], w3, acc[i]);
    }
    float* op = partial + (size_t)z * NROWS * VOCABSZ + (size_t)r0 * VOCABSZ + v;
#pragma unroll
    for (int i = 0; i < 32; ++i) op[(size_t)i * VOCABSZ] = acc[i];
}

// ---------------- per-(row,chunk): partial max, sumexp, top-8 (sums NZ split-K slabs + bias) ----------------
template<int NZ>
__global__ __launch_bounds__(256) void k_part(const float* __restrict__ partial,
                                              const float* __restrict__ bias,
                                              float* __restrict__ pm, float* __restrict__ ps,
                                              float* __restrict__ ptopv, int* __restrict__ ptopi) {
    int row = blockIdx.x, ch = blockIdx.y;
    int tid = threadIdx.x;
    const size_t slab = (size_t)NROWS * VOCABSZ;
    const float4* lr4[NZ];
#pragma unroll
    for (int zz = 0; zz < NZ; ++zz)
        lr4[zz] = (const float4*)(partial + slab * zz + (size_t)row * VOCABSZ + ch * CHUNK);
    const float4* b4 = (const float4*)(bias + ch * CHUNK);

    float va[16]; int np = 0;
    float lv[8]; int li[8];
#pragma unroll
    for (int j = 0; j < 8; ++j) { lv[j] = -INFINITY; li[j] = 0x7FFFFFFF; }

#pragma unroll
    for (int j = 0; j < 4; ++j) {
        int idx = j * 256 + tid;
        if (idx < CHUNK / 4) {
            float4 q = lr4[0][idx];
#pragma unroll
            for (int zz = 1; zz < NZ; ++zz) {
                float4 q2 = lr4[zz][idx];
                q.x += q2.x; q.y += q2.y; q.z += q2.z; q.w += q2.w;
            }
            float4 bb = b4[idx];
            q.x += bb.x; q.y += bb.y; q.z += bb.z; q.w += bb.w;
            int gi = ch * CHUNK + idx * 4;
            float vals[4] = {q.x, q.y, q.z, q.w};
#pragma unroll
            for (int c = 0; c < 4; ++c) {
                float x = vals[c];
                va[np++] = x;
                int v = gi + c;
                if (x > lv[7] || (x == lv[7] && v < li[7])) {
                    lv[7] = x; li[7] = v;
#pragma unroll
                    for (int q2 = 7; q2 > 0; --q2) {
                        bool sw = (lv[q2] > lv[q2-1]) || (lv[q2] == lv[q2-1] && li[q2] < li[q2-1]);
                        if (sw) { float tv = lv[q2]; lv[q2] = lv[q2-1]; lv[q2-1] = tv;
                                  int  ti = li[q2]; li[q2] = li[q2-1]; li[q2-1] = ti; }
                    }
                }
            }
        }
    }

    // block max
    __shared__ float sred[256];
    float m_t = -INFINITY;
    for (int j = 0; j < np; ++j) m_t = fmaxf(m_t, va[j]);
    sred[tid] = m_t;
    __syncthreads();
    for (int s = 128; s > 0; s >>= 1) { if (tid < s) sred[tid] = fmaxf(sred[tid], sred[tid+s]); __syncthreads(); }
    float m = sred[0];
    __syncthreads();

    // block sumexp (values still in registers)
    float se = 0.f;
    for (int j = 0; j < np; ++j) se += expf(va[j] - m);
    sred[tid] = se;
    __syncthreads();
    for (int s = 128; s > 0; s >>= 1) { if (tid < s) sred[tid] += sred[tid+s]; __syncthreads(); }
    if (tid == 0) { pm[row * CHUNKS + ch] = m; ps[row * CHUNKS + ch] = sred[0]; }

    // merge per-thread top-8 -> block top-8 (value desc, index asc)
    __shared__ unsigned long long skey[256];
    int pos = 0;
    float* otv = ptopv + ((size_t)row * CHUNKS + ch) * 8;
    int*   oti = ptopi + ((size_t)row * CHUNKS + ch) * 8;
    for (int r = 0; r < 8; ++r) {
        unsigned long long mykey = 0ULL;
        if (pos < 8) {
            unsigned int fb = __float_as_uint(lv[pos]);
            fb = fb ^ ((fb >> 31) ? 0xFFFFFFFFu : 0x80000000u);
            mykey = ((unsigned long long)fb << 32) | (unsigned long long)(0xFFFFFFFFu - (unsigned int)li[pos]);
        }
        skey[tid] = mykey;
        __syncthreads();
        for (int s = 128; s > 0; s >>= 1) { if (tid < s) skey[tid] = (skey[tid] > skey[tid+s]) ? skey[tid] : skey[tid+s]; __syncthreads(); }
        unsigned long long best = skey[0];
        __syncthreads();
        if (mykey == best && mykey != 0ULL) {
            otv[r] = lv[pos];
            oti[r] = li[pos];
            pos++;
        }
        __syncthreads();
    }
}

// ---------------- key pack/unpack: (ordered float << 32) | (0xFFFFFFFF - id) ----------------
__device__ inline unsigned long long packkey(float v, int idx) {
    unsigned int fb = __float_as_uint(v);
    fb = fb ^ ((fb >> 31) ? 0xFFFFFFFFu : 0x80000000u);
    return ((unsigned long long)fb << 32) | (unsigned long long)(0xFFFFFFFFu - (unsigned int)idx);
}
__device__ inline float unpack_val(unsigned long long k) {
    unsigned int fb = (unsigned int)(k >> 32);
    fb = fb ^ ((fb >> 31) ? 0x80000000u : 0xFFFFFFFFu);
    return __uint_as_float(fb);
}
__device__ inline int unpack_id(unsigned long long k) {
    return (int)(0xFFFFFFFFu - (unsigned int)(k & 0xFFFFFFFFu));
}
__device__ inline unsigned long long shflxor64(unsigned long long x, int mask) {
    unsigned int lo = (unsigned int)x, hi = (unsigned int)(x >> 32);
    lo = (unsigned int)__shfl_xor((int)lo, mask, 64);
    hi = (unsigned int)__shfl_xor((int)hi, mask, 64);
    return ((unsigned long long)hi << 32) | (unsigned long long)lo;
}
__device__ inline unsigned long long wavemax64(unsigned long long k) {
#pragma unroll
    for (int off = 1; off < 64; off <<= 1) {
        unsigned long long o = shflxor64(k, off);
        k = (o > k) ? o : k;
    }
    return k;
}

// ---------------- merge + beam bookkeeping, one block (one wave) per batch ----------------
__global__ __launch_bounds__(64) void k_mergesel(const float* __restrict__ pm, const float* __restrict__ ps,
                                                 const float* __restrict__ ptopv, const int* __restrict__ ptopi,
                                                 int* __restrict__ alive_seq, float* __restrict__ alive_lp,
                                                 int* __restrict__ fin_seq, float* __restrict__ fin_scores,
                                                 int* __restrict__ fin_flags, int* __restrict__ batch_fin, int t) {
    int b = blockIdx.x;
    int tid = threadIdx.x;
    __shared__ int aseq_old[BEAM][MAXLEN]; __shared__ int fseq_old[BEAM][MAXLEN];
    __shared__ float s_tlp[8]; __shared__ int s_ttok[8], s_tbeam[8];
    __shared__ int s_aidx[4], s_fidx[4];
    __shared__ float s_nfsc[4]; __shared__ int s_nffl[4];
    float lpen = (float)(t + 1);

    { int k = tid >> 4, p = tid & 15;
      aseq_old[k][p] = alive_seq[(b * BEAM + k) * MAXLEN + p];
      fseq_old[k][p] = fin_seq[(b * BEAM + k) * MAXLEN + p]; }

    float rv[4]; int ri[4];
#pragma unroll
    for (int k = 0; k < 4; ++k) {
        rv[k] = ptopv[(size_t)(b * BEAM + k) * 64 + tid];
        ri[k] = ptopi[(size_t)(b * BEAM + k) * 64 + tid];
    }

    float alp[4], fsc[4]; int ffl[4];
#pragma unroll
    for (int k = 0; k < 4; ++k) {
        alp[k] = alive_lp[b * BEAM + k];
        fsc[k] = fin_scores[b * BEAM + k];
        ffl[k] = fin_flags[b * BEAM + k];
    }
    int bf_old = batch_fin[b];

    float srm[4], srl[4];
#pragma unroll
    for (int k = 0; k < 4; ++k) {
        float m = -INFINITY;
#pragma unroll
        for (int c = 0; c < CHUNKS; ++c) m = fmaxf(m, pm[(b * BEAM + k) * CHUNKS + c]);
        float s = 0.f;
#pragma unroll
        for (int c = 0; c < CHUNKS; ++c) s += ps[(b * BEAM + k) * CHUNKS + c] * expf(pm[(b * BEAM + k) * CHUNKS + c] - m);
        srm[k] = m; srl[k] = logf(s);
    }

    unsigned long long key[4];
#pragma unroll
    for (int k = 0; k < 4; ++k) {
        float sh = rv[k] - srm[k];
        float lp = sh - srl[k];
        float full = alp[k] + lp;
        float cv = full / lpen;
        key[k] = packkey(cv, k * VOCABSZ + ri[k]);
    }
    {
        unsigned long long tmp;
#define CSW(a,b) if (key[b] > key[a]) { tmp = key[a]; key[a] = key[b]; key[b] = tmp; }
        CSW(0,1) CSW(2,3) CSW(0,2) CSW(1,3) CSW(1,2)
#undef CSW
    }

    float tscore[8], tlp[8]; int ttok[8], tbeam[8], tfin[8];
    int pos = 0;
#pragma unroll
    for (int r = 0; r < 8; ++r) {
        unsigned long long head = (pos == 0) ? key[0] : (pos == 1) ? key[1] :
                                  (pos == 2) ? key[2] : (pos == 3) ? key[3] : 0ULL;
        unsigned long long mx = wavemax64(head);
        if (head == mx && head != 0ULL) pos++;
        float sc = unpack_val(mx);
        int id = unpack_id(mx);
        tscore[r] = sc;
        tlp[r] = sc * lpen;
        ttok[r] = id % VOCABSZ;
        tbeam[r] = id / VOCABSZ;
        tfin[r] = (ttok[r] == EOS_TOK) ? 1 : 0;
    }

    int aidx[4];
    {
        float curr[8];
#pragma unroll
        for (int j = 0; j < 8; ++j) curr[j] = tscore[j] + (tfin[j] ? -NEGINF : 0.0f);
        unsigned int used = 0;
#pragma unroll
        for (int r = 0; r < 4; ++r) {
            float bv = 0.f; int bj = -1;
#pragma unroll
            for (int j = 0; j < 8; ++j) {
                bool skip = (used >> j) & 1u;
                bool better = !skip && (bj < 0 || curr[j] > bv);
                if (better) { bv = curr[j]; bj = j; }
            }
            used |= 1u << bj; aidx[r] = bj;
        }
    }
    int fidx[4]; float nfsc[4]; int nffl[4];
    {
        float fscand[12]; int fflcand[12];
#pragma unroll
        for (int j = 0; j < 4; ++j) { fscand[j] = fsc[j]; fflcand[j] = ffl[j]; }
#pragma unroll
        for (int q = 0; q < 8; ++q) {
            float t1 = tscore[q] + (tfin[q] ? 0.0f : -NEGINF);
            float t2 = t1 + (bf_old ? -NEGINF : 0.0f);
            fscand[4 + q] = t2; fflcand[4 + q] = tfin[q];
        }
        unsigned int used = 0;
#pragma unroll
        for (int r = 0; r < 4; ++r) {
            float bv = 0.f; int bj = -1;
#pragma unroll
            for (int j = 0; j < 12; ++j) {
                bool skip = (used >> j) & 1u;
                bool better = !skip && (bj < 0 || fscand[j] > bv);
                if (better) { bv = fscand[j]; bj = j; }
            }
            used |= 1u << bj; fidx[r] = bj;
            nfsc[r] = bv;
        }
#pragma unroll
        for (int r = 0; r < 4; ++r) {
            int bj = fidx[r]; int fl = 0;
#pragma unroll
            for (int j = 0; j < 12; ++j) if (bj == j) fl = fflcand[j];
            nffl[r] = fl;
        }
    }

    if (tid == 0) {
#pragma unroll
        for (int r = 0; r < 8; ++r) { s_tlp[r] = tlp[r]; s_ttok[r] = ttok[r]; s_tbeam[r] = tbeam[r]; }
#pragma unroll
        for (int r = 0; r < 4; ++r) { s_aidx[r] = aidx[r]; s_fidx[r] = fidx[r]; s_nfsc[r] = nfsc[r]; s_nffl[r] = nffl[r]; }
    }
    __syncthreads();

    { int k = tid >> 4, p = tid & 15;
      int j = s_aidx[k];
      int val = (p == t + 1) ? s_ttok[j] : aseq_old[s_tbeam[j]][p];
      alive_seq[(b * BEAM + k) * MAXLEN + p] = val;
      int fi = s_fidx[k]; int fval;
      if (fi < 4) fval = fseq_old[fi][p];
      else { int q = fi - 4; fval = (p == t + 1) ? s_ttok[q] : aseq_old[s_tbeam[q]][p]; }
      fin_seq[(b * BEAM + k) * MAXLEN + p] = fval; }

    if (tid < 4) {
        alive_lp[b * BEAM + tid] = s_tlp[s_aidx[tid]];
        fin_scores[b * BEAM + tid] = s_nfsc[tid];
        fin_flags[b * BEAM + tid] = s_nffl[tid];
    }
    if (tid == 0) {
        float lb = s_tlp[s_aidx[0]] / lpen;
        float lowest = nfsc[0] * (nffl[0] ? 1.f : 0.f);
        int allf = nffl[0];
#pragma unroll
        for (int k2 = 1; k2 < 4; ++k2) {
            float pz = nfsc[k2] * (nffl[k2] ? 1.f : 0.f);
            lowest = fminf(lowest, pz);
            allf = allf && nffl[k2];
        }
        lowest = lowest + (allf ? 0.f : -NEGINF);
        batch_fin[b] = bf_old || (lowest >= lb);
    }
}

// ---------------- output: fin_seq[:,0,:] as float ----------------
__global__ __launch_bounds__(256) void k_out(const int* __restrict__ fin_seq, float* __restrict__ out) {
    int tid = threadIdx.x;
    if (tid < BATCH * MAXLEN) {
        int b = tid / MAXLEN, p = tid % MAXLEN;
        out[tid] = (float)fin_seq[(b * BEAM + 0) * MAXLEN + p];
    }
}

extern "C" void kernel_launch(void* const* d_in, const int* in_sizes, int n_in,
                              void* d_out, int out_size, void* d_ws, size_t ws_size,
                              hipStream_t stream) {
    const int*   src  = (const int*)d_in[0];
    const float* Esrc = (const float*)d_in[1];
    const float* Etgt = (const float*)d_in[2];
    const float* W    = (const float*)d_in[3];
    const float* bias = (const float*)d_in[4];
    float* out = (float*)d_out;

    const size_t slab = (size_t)NROWS * VOCABSZ * 4;  // 8.192 MB
    const bool big = ws_size >= 4 * slab + (1u << 20);
    const int NZ = big ? 4 : 1;

    char* p = (char*)d_ws;
    float* partial    = (float*)p; p += NZ * slab;
    float* pooled     = (float*)p; p += BATCH * DIM * 4;
    float* xT         = (float*)p; p += DIM * NROWS * 4;
    float* pm         = (float*)p; p += NROWS * CHUNKS * 4;
    float* ps         = (float*)p; p += NROWS * CHUNKS * 4;
    float* ptopv      = (float*)p; p += NROWS * CHUNKS * 8 * 4;
    int*   ptopi      = (int*)p;   p += NROWS * CHUNKS * 8 * 4;
    int*   alive_seq  = (int*)p;   p += NROWS * MAXLEN * 4;
    int*   fin_seq    = (int*)p;   p += NROWS * MAXLEN * 4;
    float* alive_lp   = (float*)p; p += NROWS * 4;
    float* fin_scores = (float*)p; p += NROWS * 4;
    int*   fin_flags  = (int*)p;   p += NROWS * 4;
    int*   batch_fin  = (int*)p;   p += BATCH * 4;

    k_pool<<<BATCH, DIM, 0, stream>>>(src, Esrc, pooled);
    k_init<<<1, 1024, 0, stream>>>(alive_seq, alive_lp, fin_seq, fin_scores, fin_flags, batch_fin);
    for (int t = 0; t < MAXLEN - 1; ++t) {
        k_x<<<NROWS, DIM, 0, stream>>>(Etgt, pooled, alive_seq, t, xT);
        if (big) {
            k_gemm3<DIM/4><<<dim3(VOCABSZ / 128, 1, 4), 256, 0, stream>>>(xT, W, partial);
            k_part<4><<<dim3(NROWS, CHUNKS), 256, 0, stream>>>(partial, bias, pm, ps, ptopv, ptopi);
        } else {
            k_gemm3<DIM><<<dim3(VOCABSZ / 128, 1, 1), 256, 0, stream>>>(xT, W, partial);
            k_part<1><<<dim3(NROWS, CHUNKS), 256, 0, stream>>>(partial, bias, pm, ps, ptopv, ptopi);
        }
        k_mergesel<<<BATCH, 64, 0, stream>>>(pm, ps, ptopv, ptopi, alive_seq, alive_lp,
                                             fin_seq, fin_scores, fin_flags, batch_fin, t);
    }
    k_out<<<1, 256, 0, stream>>>(fin_seq, out);
}

// Round 7
// 1290.008 us; speedup vs baseline: 3.5084x; 1.0089x over previous
//
#include <hip/hip_runtime.h>
#include <math.h>

#define BATCH 16
#define SRCLEN 128
#define DIM 512
#define VOCABSZ 32000
#define BEAM 4
#define MAXLEN 16
#define NROWS (BATCH*BEAM)   // 64
#define BOS_TOK 1
#define EOS_TOK 2
#define NEGINF 1e9f
#define CHUNKS 8
#define CHUNK 4000           // VOCABSZ / CHUNKS
#define PCH 8                // pool s-chunks
#define PCL (SRCLEN/PCH)     // 16 s per chunk

// ---------------- encoder pool, phase 1: per-(b, s-chunk) partial sum + count ----------------
// R6 post-mortem: old k_pool = 16 blocks x 128-deep serial dependent-load chain
// -> 59.5us at 1.27% occupancy. Now 128 blocks, chain depth 16, tokens arrive
// as one s_load_dwordx16. Chunk-reassociation of the s-sum: ~1e-6 perturbation.
__global__ __launch_bounds__(512) void k_pool2(const int* __restrict__ src,
                                               const float* __restrict__ Esrc,
                                               float* __restrict__ pp, float* __restrict__ pcnt) {
    int b = blockIdx.x, c = blockIdx.y;
    int d = threadIdx.x;
    float acc = 0.f, cnt = 0.f;
#pragma unroll
    for (int s = 0; s < PCL; ++s) {
        int tok = src[b * SRCLEN + c * PCL + s];
        if (tok != 0) { acc += Esrc[(size_t)tok * DIM + d]; cnt += 1.f; }
    }
    pp[(b * PCH + c) * DIM + d] = acc;
    if (d == 0) pcnt[b * PCH + c] = cnt;
}

// ---------------- encoder pool, phase 2: reduce chunks (ascending, deterministic) ----------------
__global__ __launch_bounds__(512) void k_poolred(const float* __restrict__ pp,
                                                 const float* __restrict__ pcnt,
                                                 float* __restrict__ pooled) {
    int b = blockIdx.x;
    int d = threadIdx.x;
    float acc = 0.f, cnt = 0.f;
#pragma unroll
    for (int c = 0; c < PCH; ++c) { acc += pp[(b * PCH + c) * DIM + d]; cnt += pcnt[b * PCH + c]; }
    pooled[b * DIM + d] = acc / fmaxf(cnt, 1.f);
}

// ---------------- state init ----------------
__global__ __launch_bounds__(1024) void k_init(int* __restrict__ alive_seq, float* __restrict__ alive_lp,
                                               int* __restrict__ fin_seq, float* __restrict__ fin_scores,
                                               int* __restrict__ fin_flags, int* __restrict__ batch_fin) {
    int tid = threadIdx.x;  // 1024 = NROWS*MAXLEN
    alive_seq[tid] = (tid % MAXLEN == 0) ? BOS_TOK : 0;
    fin_seq[tid] = 0;
    if (tid < NROWS) {
        alive_lp[tid] = (tid % BEAM == 0) ? 0.f : -INFINITY;
        fin_scores[tid] = -NEGINF;
        fin_flags[tid] = 0;
    }
    if (tid < BATCH) batch_fin[tid] = 0;
}

// ---------------- decoder input, transposed: xT[d][i] = E_tgt[last_i][d] + pooled[i/4][d] ----------------
__global__ __launch_bounds__(512) void k_x(const float* __restrict__ Etgt,
                                           const float* __restrict__ pooled,
                                           const int* __restrict__ alive_seq, int t,
                                           float* __restrict__ xT) {
    int i = blockIdx.x;   // row 0..63
    int d = threadIdx.x;  // 0..511
    int last = alive_seq[i * MAXLEN + t];
    float v = Etgt[(size_t)last * DIM + d] + pooled[(i >> 2) * DIM + d];
    xT[d * NROWS + i] = v;
}

// ---------------- logits GEMM, split-K, 16-row threads ----------------
// R7: thread = 1v x 16 rows (acc[16], ~40 VGPR -> no spill, 8 waves/SIMD OK);
// block = 64v x 4 row-quarters; grid 500 x 4 = 2000 blocks -> ~31 waves/CU
// (R6 had 4/SIMD). x-side: 64 floats per 4-d iter fits the SGPR file (R6's
// 128/iter did not -> serialized lgkm waits). d-order per slab unchanged ->
// partials bit-identical to R6.
template<int DLEN>
__global__ __launch_bounds__(256) void k_gemm4(const float* __restrict__ xT,
                                               const float* __restrict__ W,
                                               float* __restrict__ partial) {
    int v  = blockIdx.x * 64 + (threadIdx.x & 63);
    int rq = __builtin_amdgcn_readfirstlane(threadIdx.x >> 6);  // wave-uniform row quarter
    int r0 = rq * 16;
    int z  = blockIdx.z;
    int d0 = z * DLEN;
    float acc[16];
#pragma unroll
    for (int i = 0; i < 16; ++i) acc[i] = 0.f;
    const float* wp = W + (size_t)d0 * VOCABSZ + v;
    const float* xp = xT + (size_t)d0 * NROWS + r0;
    for (int dd = 0; dd < DLEN; dd += 4) {
        float w0 = wp[0];
        float w1 = wp[(size_t)VOCABSZ];
        float w2 = wp[(size_t)2 * VOCABSZ];
        float w3 = wp[(size_t)3 * VOCABSZ];
        wp += (size_t)4 * VOCABSZ;
        const float* x0 = xp;
        const float* x1 = xp + NROWS;
        const float* x2 = xp + 2 * NROWS;
        const float* x3 = xp + 3 * NROWS;
        xp += 4 * NROWS;
#pragma unroll
        for (int i = 0; i < 16; ++i) acc[i] = fmaf(x0[i], w0, acc[i]);
#pragma unroll
        for (int i = 0; i < 16; ++i) acc[i] = fmaf(x1[i], w1, acc[i]);
#pragma unroll
        for (int i = 0; i < 16; ++i) acc[i] = fmaf(x2[i], w2, acc[i]);
#pragma unroll
        for (int i = 0; i < 16; ++i) acc[i] = fmaf(x3[i], w3, acc[i]);
    }
    float* op = partial + (size_t)z * NROWS * VOCABSZ + (size_t)r0 * VOCABSZ + v;
#pragma unroll
    for (int i = 0; i < 16; ++i) op[(size_t)i * VOCABSZ] = acc[i];
}

// ---------------- per-(row,chunk): partial max, sumexp, top-8 (sums NZ split-K slabs + bias) ----------------
template<int NZ>
__global__ __launch_bounds__(256) void k_part(const float* __restrict__ partial,
                                              const float* __restrict__ bias,
                                              float* __restrict__ pm, float* __restrict__ ps,
                                              float* __restrict__ ptopv, int* __restrict__ ptopi) {
    int row = blockIdx.x, ch = blockIdx.y;
    int tid = threadIdx.x;
    const size_t slab = (size_t)NROWS * VOCABSZ;
    const float4* lr4[NZ];
#pragma unroll
    for (int zz = 0; zz < NZ; ++zz)
        lr4[zz] = (const float4*)(partial + slab * zz + (size_t)row * VOCABSZ + ch * CHUNK);
    const float4* b4 = (const float4*)(bias + ch * CHUNK);

    float va[16]; int np = 0;
    float lv[8]; int li[8];
#pragma unroll
    for (int j = 0; j < 8; ++j) { lv[j] = -INFINITY; li[j] = 0x7FFFFFFF; }

#pragma unroll
    for (int j = 0; j < 4; ++j) {
        int idx = j * 256 + tid;
        if (idx < CHUNK / 4) {
            float4 q = lr4[0][idx];
#pragma unroll
            for (int zz = 1; zz < NZ; ++zz) {
                float4 q2 = lr4[zz][idx];
                q.x += q2.x; q.y += q2.y; q.z += q2.z; q.w += q2.w;
            }
            float4 bb = b4[idx];
            q.x += bb.x; q.y += bb.y; q.z += bb.z; q.w += bb.w;
            int gi = ch * CHUNK + idx * 4;
            float vals[4] = {q.x, q.y, q.z, q.w};
#pragma unroll
            for (int c = 0; c < 4; ++c) {
                float x = vals[c];
                va[np++] = x;
                int v = gi + c;
                if (x > lv[7] || (x == lv[7] && v < li[7])) {
                    lv[7] = x; li[7] = v;
#pragma unroll
                    for (int q2 = 7; q2 > 0; --q2) {
                        bool sw = (lv[q2] > lv[q2-1]) || (lv[q2] == lv[q2-1] && li[q2] < li[q2-1]);
                        if (sw) { float tv = lv[q2]; lv[q2] = lv[q2-1]; lv[q2-1] = tv;
                                  int  ti = li[q2]; li[q2] = li[q2-1]; li[q2-1] = ti; }
                    }
                }
            }
        }
    }

    // block max
    __shared__ float sred[256];
    float m_t = -INFINITY;
    for (int j = 0; j < np; ++j) m_t = fmaxf(m_t, va[j]);
    sred[tid] = m_t;
    __syncthreads();
    for (int s = 128; s > 0; s >>= 1) { if (tid < s) sred[tid] = fmaxf(sred[tid], sred[tid+s]); __syncthreads(); }
    float m = sred[0];
    __syncthreads();

    // block sumexp (values still in registers)
    float se = 0.f;
    for (int j = 0; j < np; ++j) se += expf(va[j] - m);
    sred[tid] = se;
    __syncthreads();
    for (int s = 128; s > 0; s >>= 1) { if (tid < s) sred[tid] += sred[tid+s]; __syncthreads(); }
    if (tid == 0) { pm[row * CHUNKS + ch] = m; ps[row * CHUNKS + ch] = sred[0]; }

    // merge per-thread top-8 -> block top-8 (value desc, index asc)
    __shared__ unsigned long long skey[256];
    int pos = 0;
    float* otv = ptopv + ((size_t)row * CHUNKS + ch) * 8;
    int*   oti = ptopi + ((size_t)row * CHUNKS + ch) * 8;
    for (int r = 0; r < 8; ++r) {
        unsigned long long mykey = 0ULL;
        if (pos < 8) {
            unsigned int fb = __float_as_uint(lv[pos]);
            fb = fb ^ ((fb >> 31) ? 0xFFFFFFFFu : 0x80000000u);
            mykey = ((unsigned long long)fb << 32) | (unsigned long long)(0xFFFFFFFFu - (unsigned int)li[pos]);
        }
        skey[tid] = mykey;
        __syncthreads();
        for (int s = 128; s > 0; s >>= 1) { if (tid < s) skey[tid] = (skey[tid] > skey[tid+s]) ? skey[tid] : skey[tid+s]; __syncthreads(); }
        unsigned long long best = skey[0];
        __syncthreads();
        if (mykey == best && mykey != 0ULL) {
            otv[r] = lv[pos];
            oti[r] = li[pos];
            pos++;
        }
        __syncthreads();
    }
}

// ---------------- key pack/unpack: (ordered float << 32) | (0xFFFFFFFF - id) ----------------
__device__ inline unsigned long long packkey(float v, int idx) {
    unsigned int fb = __float_as_uint(v);
    fb = fb ^ ((fb >> 31) ? 0xFFFFFFFFu : 0x80000000u);
    return ((unsigned long long)fb << 32) | (unsigned long long)(0xFFFFFFFFu - (unsigned int)idx);
}
__device__ inline float unpack_val(unsigned long long k) {
    unsigned int fb = (unsigned int)(k >> 32);
    fb = fb ^ ((fb >> 31) ? 0x80000000u : 0xFFFFFFFFu);
    return __uint_as_float(fb);
}
__device__ inline int unpack_id(unsigned long long k) {
    return (int)(0xFFFFFFFFu - (unsigned int)(k & 0xFFFFFFFFu));
}
__device__ inline unsigned long long shflxor64(unsigned long long x, int mask) {
    unsigned int lo = (unsigned int)x, hi = (unsigned int)(x >> 32);
    lo = (unsigned int)__shfl_xor((int)lo, mask, 64);
    hi = (unsigned int)__shfl_xor((int)hi, mask, 64);
    return ((unsigned long long)hi << 32) | (unsigned long long)lo;
}
__device__ inline unsigned long long wavemax64(unsigned long long k) {
#pragma unroll
    for (int off = 1; off < 64; off <<= 1) {
        unsigned long long o = shflxor64(k, off);
        k = (o > k) ? o : k;
    }
    return k;
}

// ---------------- merge + beam bookkeeping, one block (one wave) per batch ----------------
__global__ __launch_bounds__(64) void k_mergesel(const float* __restrict__ pm, const float* __restrict__ ps,
                                                 const float* __restrict__ ptopv, const int* __restrict__ ptopi,
                                                 int* __restrict__ alive_seq, float* __restrict__ alive_lp,
                                                 int* __restrict__ fin_seq, float* __restrict__ fin_scores,
                                                 int* __restrict__ fin_flags, int* __restrict__ batch_fin, int t) {
    int b = blockIdx.x;
    int tid = threadIdx.x;
    __shared__ int aseq_old[BEAM][MAXLEN]; __shared__ int fseq_old[BEAM][MAXLEN];
    __shared__ float s_tlp[8]; __shared__ int s_ttok[8], s_tbeam[8];
    __shared__ int s_aidx[4], s_fidx[4];
    __shared__ float s_nfsc[4]; __shared__ int s_nffl[4];
    float lpen = (float)(t + 1);

    { int k = tid >> 4, p = tid & 15;
      aseq_old[k][p] = alive_seq[(b * BEAM + k) * MAXLEN + p];
      fseq_old[k][p] = fin_seq[(b * BEAM + k) * MAXLEN + p]; }

    float rv[4]; int ri[4];
#pragma unroll
    for (int k = 0; k < 4; ++k) {
        rv[k] = ptopv[(size_t)(b * BEAM + k) * 64 + tid];
        ri[k] = ptopi[(size_t)(b * BEAM + k) * 64 + tid];
    }

    float alp[4], fsc[4]; int ffl[4];
#pragma unroll
    for (int k = 0; k < 4; ++k) {
        alp[k] = alive_lp[b * BEAM + k];
        fsc[k] = fin_scores[b * BEAM + k];
        ffl[k] = fin_flags[b * BEAM + k];
    }
    int bf_old = batch_fin[b];

    float srm[4], srl[4];
#pragma unroll
    for (int k = 0; k < 4; ++k) {
        float m = -INFINITY;
#pragma unroll
        for (int c = 0; c < CHUNKS; ++c) m = fmaxf(m, pm[(b * BEAM + k) * CHUNKS + c]);
        float s = 0.f;
#pragma unroll
        for (int c = 0; c < CHUNKS; ++c) s += ps[(b * BEAM + k) * CHUNKS + c] * expf(pm[(b * BEAM + k) * CHUNKS + c] - m);
        srm[k] = m; srl[k] = logf(s);
    }

    unsigned long long key[4];
#pragma unroll
    for (int k = 0; k < 4; ++k) {
        float sh = rv[k] - srm[k];
        float lp = sh - srl[k];
        float full = alp[k] + lp;
        float cv = full / lpen;
        key[k] = packkey(cv, k * VOCABSZ + ri[k]);
    }
    {
        unsigned long long tmp;
#define CSW(a,b) if (key[b] > key[a]) { tmp = key[a]; key[a] = key[b]; key[b] = tmp; }
        CSW(0,1) CSW(2,3) CSW(0,2) CSW(1,3) CSW(1,2)
#undef CSW
    }

    float tscore[8], tlp[8]; int ttok[8], tbeam[8], tfin[8];
    int pos = 0;
#pragma unroll
    for (int r = 0; r < 8; ++r) {
        unsigned long long head = (pos == 0) ? key[0] : (pos == 1) ? key[1] :
                                  (pos == 2) ? key[2] : (pos == 3) ? key[3] : 0ULL;
        unsigned long long mx = wavemax64(head);
        if (head == mx && head != 0ULL) pos++;
        float sc = unpack_val(mx);
        int id = unpack_id(mx);
        tscore[r] = sc;
        tlp[r] = sc * lpen;
        ttok[r] = id % VOCABSZ;
        tbeam[r] = id / VOCABSZ;
        tfin[r] = (ttok[r] == EOS_TOK) ? 1 : 0;
    }

    int aidx[4];
    {
        float curr[8];
#pragma unroll
        for (int j = 0; j < 8; ++j) curr[j] = tscore[j] + (tfin[j] ? -NEGINF : 0.0f);
        unsigned int used = 0;
#pragma unroll
        for (int r = 0; r < 4; ++r) {
            float bv = 0.f; int bj = -1;
#pragma unroll
            for (int j = 0; j < 8; ++j) {
                bool skip = (used >> j) & 1u;
                bool better = !skip && (bj < 0 || curr[j] > bv);
                if (better) { bv = curr[j]; bj = j; }
            }
            used |= 1u << bj; aidx[r] = bj;
        }
    }
    int fidx[4]; float nfsc[4]; int nffl[4];
    {
        float fscand[12]; int fflcand[12];
#pragma unroll
        for (int j = 0; j < 4; ++j) { fscand[j] = fsc[j]; fflcand[j] = ffl[j]; }
#pragma unroll
        for (int q = 0; q < 8; ++q) {
            float t1 = tscore[q] + (tfin[q] ? 0.0f : -NEGINF);
            float t2 = t1 + (bf_old ? -NEGINF : 0.0f);
            fscand[4 + q] = t2; fflcand[4 + q] = tfin[q];
        }
        unsigned int used = 0;
#pragma unroll
        for (int r = 0; r < 4; ++r) {
            float bv = 0.f; int bj = -1;
#pragma unroll
            for (int j = 0; j < 12; ++j) {
                bool skip = (used >> j) & 1u;
                bool better = !skip && (bj < 0 || fscand[j] > bv);
                if (better) { bv = fscand[j]; bj = j; }
            }
            used |= 1u << bj; fidx[r] = bj;
            nfsc[r] = bv;
        }
#pragma unroll
        for (int r = 0; r < 4; ++r) {
            int bj = fidx[r]; int fl = 0;
#pragma unroll
            for (int j = 0; j < 12; ++j) if (bj == j) fl = fflcand[j];
            nffl[r] = fl;
        }
    }

    if (tid == 0) {
#pragma unroll
        for (int r = 0; r < 8; ++r) { s_tlp[r] = tlp[r]; s_ttok[r] = ttok[r]; s_tbeam[r] = tbeam[r]; }
#pragma unroll
        for (int r = 0; r < 4; ++r) { s_aidx[r] = aidx[r]; s_fidx[r] = fidx[r]; s_nfsc[r] = nfsc[r]; s_nffl[r] = nffl[r]; }
    }
    __syncthreads();

    { int k = tid >> 4, p = tid & 15;
      int j = s_aidx[k];
      int val = (p == t + 1) ? s_ttok[j] : aseq_old[s_tbeam[j]][p];
      alive_seq[(b * BEAM + k) * MAXLEN + p] = val;
      int fi = s_fidx[k]; int fval;
      if (fi < 4) fval = fseq_old[fi][p];
      else { int q = fi - 4; fval = (p == t + 1) ? s_ttok[q] : aseq_old[s_tbeam[q]][p]; }
      fin_seq[(b * BEAM + k) * MAXLEN + p] = fval; }

    if (tid < 4) {
        alive_lp[b * BEAM + tid] = s_tlp[s_aidx[tid]];
        fin_scores[b * BEAM + tid] = s_nfsc[tid];
        fin_flags[b * BEAM + tid] = s_nffl[tid];
    }
    if (tid == 0) {
        float lb = s_tlp[s_aidx[0]] / lpen;
        float lowest = nfsc[0] * (nffl[0] ? 1.f : 0.f);
        int allf = nffl[0];
#pragma unroll
        for (int k2 = 1; k2 < 4; ++k2) {
            float pz = nfsc[k2] * (nffl[k2] ? 1.f : 0.f);
            lowest = fminf(lowest, pz);
            allf = allf && nffl[k2];
        }
        lowest = lowest + (allf ? 0.f : -NEGINF);
        batch_fin[b] = bf_old || (lowest >= lb);
    }
}

// ---------------- output: fin_seq[:,0,:] as float ----------------
__global__ __launch_bounds__(256) void k_out(const int* __restrict__ fin_seq, float* __restrict__ out) {
    int tid = threadIdx.x;
    if (tid < BATCH * MAXLEN) {
        int b = tid / MAXLEN, p = tid % MAXLEN;
        out[tid] = (float)fin_seq[(b * BEAM + 0) * MAXLEN + p];
    }
}

extern "C" void kernel_launch(void* const* d_in, const int* in_sizes, int n_in,
                              void* d_out, int out_size, void* d_ws, size_t ws_size,
                              hipStream_t stream) {
    const int*   src  = (const int*)d_in[0];
    const float* Esrc = (const float*)d_in[1];
    const float* Etgt = (const float*)d_in[2];
    const float* W    = (const float*)d_in[3];
    const float* bias = (const float*)d_in[4];
    float* out = (float*)d_out;

    const size_t slab = (size_t)NROWS * VOCABSZ * 4;  // 8.192 MB
    const bool big = ws_size >= 4 * slab + (1u << 20);
    const int NZ = big ? 4 : 1;

    char* p = (char*)d_ws;
    float* partial    = (float*)p; p += NZ * slab;
    float* pooled     = (float*)p; p += BATCH * DIM * 4;
    float* xT         = (float*)p; p += DIM * NROWS * 4;
    float* pp         = (float*)p; p += BATCH * PCH * DIM * 4;   // 256 KB
    float* pcnt       = (float*)p; p += BATCH * PCH * 4;
    float* pm         = (float*)p; p += NROWS * CHUNKS * 4;
    float* ps         = (float*)p; p += NROWS * CHUNKS * 4;
    float* ptopv      = (float*)p; p += NROWS * CHUNKS * 8 * 4;
    int*   ptopi      = (int*)p;   p += NROWS * CHUNKS * 8 * 4;
    int*   alive_seq  = (int*)p;   p += NROWS * MAXLEN * 4;
    int*   fin_seq    = (int*)p;   p += NROWS * MAXLEN * 4;
    float* alive_lp   = (float*)p; p += NROWS * 4;
    float* fin_scores = (float*)p; p += NROWS * 4;
    int*   fin_flags  = (int*)p;   p += NROWS * 4;
    int*   batch_fin  = (int*)p;   p += BATCH * 4;

    k_pool2<<<dim3(BATCH, PCH), DIM, 0, stream>>>(src, Esrc, pp, pcnt);
    k_poolred<<<BATCH, DIM, 0, stream>>>(pp, pcnt, pooled);
    k_init<<<1, 1024, 0, stream>>>(alive_seq, alive_lp, fin_seq, fin_scores, fin_flags, batch_fin);
    for (int t = 0; t < MAXLEN - 1; ++t) {
        k_x<<<NROWS, DIM, 0, stream>>>(Etgt, pooled, alive_seq, t, xT);
        if (big) {
            k_gemm4<DIM/4><<<dim3(VOCABSZ / 64, 1, 4), 256, 0, stream>>>(xT, W, partial);
            k_part<4><<<dim3(NROWS, CHUNKS), 256, 0, stream>>>(partial, bias, pm, ps, ptopv, ptopi);
        } else {
            k_gemm4<DIM><<<dim3(VOCABSZ / 64, 1, 1), 256, 0, stream>>>(xT, W, partial);
            k_part<1><<<dim3(NROWS, CHUNKS), 256, 0, stream>>>(partial, bias, pm, ps, ptopv, ptopi);
        }
        k_mergesel<<<BATCH, 64, 0, stream>>>(pm, ps, ptopv, ptopi, alive_seq, alive_lp,
                                             fin_seq, fin_scores, fin_flags, batch_fin, t);
    }
    k_out<<<1, 256, 0, stream>>>(fin_seq, out);
}